// Round 1
// baseline (804.392 us; speedup 1.0000x reference)
//
#include <hip/hip_runtime.h>

// Problem constants (fixed by the reference)
constexpr int L = 8192;          // nodes
constexpr int H = 4;             // heads (both layers)

static __device__ __forceinline__ float lrelu(float e) {
  return e > 0.f ? e : 0.2f * e;
}

// ---------------- dense GEMM: C = op(A[MxK] @ B[KxN]) ----------------
template<bool RELU>
__global__ __launch_bounds__(256) void gemm_tiled(
    const float* __restrict__ A, const float* __restrict__ B,
    float* __restrict__ C, int M, int N, int K) {
  __shared__ float As[16][64];
  __shared__ float Bs[16][64];
  int tid = threadIdx.x;
  int m0 = blockIdx.y * 64, n0 = blockIdx.x * 64;
  int tx = tid & 15, ty = tid >> 4;
  float acc[4][4] = {};
  for (int k0 = 0; k0 < K; k0 += 16) {
#pragma unroll
    for (int i = 0; i < 4; i++) {
      int e = tid + i * 256; int r = e >> 4, kk = e & 15;
      int gr = m0 + r, gk = k0 + kk;
      As[kk][r] = (gr < M && gk < K) ? A[(size_t)gr * K + gk] : 0.f;
    }
#pragma unroll
    for (int i = 0; i < 4; i++) {
      int e = tid + i * 256; int kk = e >> 6, c = e & 63;
      int gk = k0 + kk, gc = n0 + c;
      Bs[kk][c] = (gk < K && gc < N) ? B[(size_t)gk * N + gc] : 0.f;
    }
    __syncthreads();
#pragma unroll
    for (int k = 0; k < 16; k++) {
      float a[4], b[4];
#pragma unroll
      for (int i = 0; i < 4; i++) { a[i] = As[k][ty * 4 + i]; b[i] = Bs[k][tx * 4 + i]; }
#pragma unroll
      for (int i = 0; i < 4; i++)
#pragma unroll
        for (int j = 0; j < 4; j++)
          acc[i][j] = fmaf(a[i], b[j], acc[i][j]);
    }
    __syncthreads();
  }
#pragma unroll
  for (int i = 0; i < 4; i++) {
    int gr = m0 + ty * 4 + i;
    if (gr >= M) continue;
#pragma unroll
    for (int j = 0; j < 4; j++) {
      int gc = n0 + tx * 4 + j;
      if (gc >= N) continue;
      float v = acc[i][j];
      C[(size_t)gr * N + gc] = RELU ? fmaxf(v, 0.f) : v;
    }
  }
}

// ---------------- CSR build (counting sort by dst) ----------------
__global__ void count_deg(const int* __restrict__ ei, int E, int Etot,
                          int* __restrict__ deg) {
  int e = blockIdx.x * blockDim.x + threadIdx.x;
  if (e >= Etot) return;
  int dst = (e < E) ? ei[E + e] : (e - E);
  atomicAdd(&deg[dst], 1);
}

__global__ __launch_bounds__(1024) void scan_deg(const int* __restrict__ deg,
                                                 int* __restrict__ row_start) {
  __shared__ int part[1024];
  int tid = threadIdx.x;
  int local[8];
  int sum = 0;
#pragma unroll
  for (int j = 0; j < 8; j++) { local[j] = deg[tid * 8 + j]; sum += local[j]; }
  part[tid] = sum;
  __syncthreads();
  for (int off = 1; off < 1024; off <<= 1) {
    int v = part[tid];
    int add = (tid >= off) ? part[tid - off] : 0;
    __syncthreads();
    part[tid] = v + add;
    __syncthreads();
  }
  int base = part[tid] - sum;  // exclusive prefix
#pragma unroll
  for (int j = 0; j < 8; j++) { row_start[tid * 8 + j] = base; base += local[j]; }
  if (tid == 1023) row_start[L] = part[1023];
}

__global__ void scatter_edges(const int* __restrict__ ei, int E, int Etot,
                              const int* __restrict__ row_start,
                              int* __restrict__ cursor, int* __restrict__ csr_src) {
  int e = blockIdx.x * blockDim.x + threadIdx.x;
  if (e >= Etot) return;
  int srcv, dstv;
  if (e < E) { srcv = ei[e]; dstv = ei[E + e]; } else { srcv = dstv = e - E; }
  int pos = row_start[dstv] + atomicAdd(&cursor[dstv], 1);
  csr_src[pos] = srcv;
}

// ---------------- attention coefficients a_s, a_d per node/head ----------------
__global__ void attn_coef(const float* __restrict__ hfeat,
                          const float* __restrict__ asrc, const float* __restrict__ adst,
                          float* __restrict__ a_s, float* __restrict__ a_d,
                          int HC, int C) {
  extern __shared__ float red[];  // 2*HC floats
  int n = blockIdx.x, tid = threadIdx.x;
  float hv = hfeat[(size_t)n * HC + tid];
  red[tid] = hv * asrc[tid];
  red[HC + tid] = hv * adst[tid];
  __syncthreads();
  for (int s = C >> 1; s > 0; s >>= 1) {
    if ((tid & (C - 1)) < s) {
      red[tid] += red[tid + s];
      red[HC + tid] += red[HC + tid + s];
    }
    __syncthreads();
  }
  if ((tid & (C - 1)) == 0) {
    int h = tid / C;
    a_s[n * H + h] = red[tid];
    a_d[n * H + h] = red[HC + tid];
  }
}

// ---------------- per-node online softmax stats (one wave per node) ----------------
__global__ __launch_bounds__(64) void softmax_stats(
    const float* __restrict__ a_s, const float* __restrict__ a_d,
    const int* __restrict__ row_start, const int* __restrict__ csr_src,
    float* __restrict__ mout, float* __restrict__ invden) {
  int n = blockIdx.x, lane = threadIdx.x;
  int rs = row_start[n], re = row_start[n + 1];
  const float4 adn4 = *reinterpret_cast<const float4*>(&a_d[n * H]);
  float adn[4] = {adn4.x, adn4.y, adn4.z, adn4.w};
  float m[4], s[4];
#pragma unroll
  for (int h = 0; h < 4; h++) { m[h] = -1e30f; s[h] = 0.f; }
  for (int i = rs + lane; i < re; i += 64) {
    int sr = csr_src[i];
    const float4 as4 = *reinterpret_cast<const float4*>(&a_s[sr * H]);
    float asv[4] = {as4.x, as4.y, as4.z, as4.w};
#pragma unroll
    for (int h = 0; h < 4; h++) {
      float e = lrelu(asv[h] + adn[h]);
      if (e > m[h]) { s[h] = s[h] * __expf(m[h] - e) + 1.f; m[h] = e; }
      else s[h] += __expf(e - m[h]);
    }
  }
#pragma unroll
  for (int off = 32; off > 0; off >>= 1) {
#pragma unroll
    for (int h = 0; h < 4; h++) {
      float om = __shfl_xor(m[h], off);
      float os = __shfl_xor(s[h], off);
      float M = fmaxf(m[h], om);
      s[h] = s[h] * __expf(m[h] - M) + os * __expf(om - M);
      m[h] = M;
    }
  }
  if (lane == 0) {
#pragma unroll
    for (int h = 0; h < 4; h++) {
      mout[n * H + h] = m[h];
      invden[n * H + h] = 1.f / (s[h] + 1e-16f);
    }
  }
}

// ---------------- weighted aggregation + bias + relu ----------------
template<int C>
__global__ void gat_aggregate(
    const float* __restrict__ hfeat, const float* __restrict__ a_s,
    const float* __restrict__ a_d, const float* __restrict__ m,
    const float* __restrict__ invden, const int* __restrict__ row_start,
    const int* __restrict__ csr_src, const float* __restrict__ bias,
    float* __restrict__ out) {
  constexpr int HC = H * C;
  int n = blockIdx.x, tid = threadIdx.x;
  int h = tid / C;
  float adn = a_d[n * H + h], mh = m[n * H + h], inv = invden[n * H + h];
  int rs = row_start[n], re = row_start[n + 1];
  float acc = 0.f;
  for (int i = rs; i < re; i++) {
    int sr = csr_src[i];
    float e = lrelu(a_s[sr * H + h] + adn);
    float al = __expf(e - mh) * inv;
    acc = fmaf(al, hfeat[(size_t)sr * HC + tid], acc);
  }
  out[(size_t)n * HC + tid] = fmaxf(acc + bias[tid], 0.f);
}

// ---------------- pooled column sum ----------------
__global__ __launch_bounds__(512) void col_sum(const float* __restrict__ x,
                                               float* __restrict__ pooled) {
  int t = threadIdx.x;
  float acc = 0.f;
  for (int r = blockIdx.x; r < L; r += gridDim.x) acc += x[(size_t)r * 512 + t];
  atomicAdd(&pooled[t], acc);
}

// ---------------- small FC layers ----------------
__global__ __launch_bounds__(512) void fc_relu(const float* __restrict__ in,
                                               const float* __restrict__ W,
                                               const float* __restrict__ b,
                                               float* __restrict__ out) {
  __shared__ float pv[512];
  int t = threadIdx.x;
  pv[t] = in[t];
  __syncthreads();
  float acc = 0.f;
  for (int k = 0; k < 512; k++) acc = fmaf(pv[k], W[k * 512 + t], acc);
  out[t] = fmaxf(acc + b[t], 0.f);
}

__global__ __launch_bounds__(512) void fc_out(const float* __restrict__ hin,
                                              const float* __restrict__ W,
                                              const float* __restrict__ b,
                                              float* __restrict__ out) {
  __shared__ float pv[512];
  int t = threadIdx.x;
  pv[t] = hin[t];
  __syncthreads();
  if (t < 489) {
    float acc = 0.f;
    for (int k = 0; k < 512; k++) acc = fmaf(pv[k], W[k * 489 + t], acc);
    out[t] = acc + b[t];
  }
}

extern "C" void kernel_launch(void* const* d_in, const int* in_sizes, int n_in,
                              void* d_out, int out_size, void* d_ws, size_t ws_size,
                              hipStream_t stream) {
  const float* seq   = (const float*)d_in[0];
  const int*   ei    = (const int*)d_in[1];
  const float* W1    = (const float*)d_in[2];
  const float* W2    = (const float*)d_in[3];
  const float* Wg1   = (const float*)d_in[4];
  const float* asrc1 = (const float*)d_in[5];
  const float* adst1 = (const float*)d_in[6];
  const float* b1    = (const float*)d_in[7];
  const float* Wg2   = (const float*)d_in[8];
  const float* asrc2 = (const float*)d_in[9];
  const float* adst2 = (const float*)d_in[10];
  const float* b2    = (const float*)d_in[11];
  const float* fcW   = (const float*)d_in[12];
  const float* fcb   = (const float*)d_in[13];
  const float* outW  = (const float*)d_in[14];
  const float* outb  = (const float*)d_in[15];
  float* outp = (float*)d_out;

  const int E = in_sizes[1] / 2;      // 524288
  const int Etot = E + L;             // + self loops

  // ---- workspace layout ----
  char* ws = (char*)d_ws;
  float* C1   = (float*)(ws + 0);                  // [L,1024] 32MB (reused below)
  float* h2   = (float*)(ws + 0);                  // [L,512] 16MB
  float* out2 = (float*)(ws + 16777216);           // [L,512] 16MB
  size_t off = 33554432;
  float* x0   = (float*)(ws + off); off += (size_t)L * 256 * 4;   // 8MB
  float* h1   = (float*)(ws + off); off += (size_t)L * 256 * 4;   // 8MB
  float* out1 = (float*)(ws + off); off += (size_t)L * 256 * 4;   // 8MB
  int* csr_src   = (int*)(ws + off); off += (size_t)Etot * 4;
  off = (off + 255) & ~(size_t)255;
  int* row_start = (int*)(ws + off); off += (size_t)(L + 1) * 4;
  off = (off + 255) & ~(size_t)255;
  int* deg    = (int*)(ws + off); off += (size_t)L * 4;
  int* cursor = (int*)(ws + off); off += (size_t)L * 4;   // adjacent to deg
  float* a_s1 = (float*)(ws + off); off += (size_t)L * H * 4;
  float* a_d1 = (float*)(ws + off); off += (size_t)L * H * 4;
  float* m1   = (float*)(ws + off); off += (size_t)L * H * 4;
  float* inv1 = (float*)(ws + off); off += (size_t)L * H * 4;
  float* a_s2 = (float*)(ws + off); off += (size_t)L * H * 4;
  float* a_d2 = (float*)(ws + off); off += (size_t)L * H * 4;
  float* m2   = (float*)(ws + off); off += (size_t)L * H * 4;
  float* inv2 = (float*)(ws + off); off += (size_t)L * H * 4;
  float* pooled = (float*)(ws + off); off += 512 * 4;
  float* hbuf   = (float*)(ws + off); off += 512 * 4;

  // ---- zero the accumulators used this call ----
  hipMemsetAsync(deg, 0, (size_t)L * 8, stream);        // deg + cursor
  hipMemsetAsync(pooled, 0, 512 * 4, stream);

  // ---- input MLP ----
  gemm_tiled<true><<<dim3(1024 / 64, L / 64), 256, 0, stream>>>(seq, W1, C1, L, 1024, 26);
  gemm_tiled<false><<<dim3(256 / 64, L / 64), 256, 0, stream>>>(C1, W2, x0, L, 256, 1024);

  // ---- CSR build ----
  int eb = (Etot + 255) / 256;
  count_deg<<<eb, 256, 0, stream>>>(ei, E, Etot, deg);
  scan_deg<<<1, 1024, 0, stream>>>(deg, row_start);
  scatter_edges<<<eb, 256, 0, stream>>>(ei, E, Etot, row_start, cursor, csr_src);

  // ---- GAT layer 1 (C=64, HC=256) ----
  gemm_tiled<false><<<dim3(256 / 64, L / 64), 256, 0, stream>>>(x0, Wg1, h1, L, 256, 256);
  attn_coef<<<L, 256, 2 * 256 * 4, stream>>>(h1, asrc1, adst1, a_s1, a_d1, 256, 64);
  softmax_stats<<<L, 64, 0, stream>>>(a_s1, a_d1, row_start, csr_src, m1, inv1);
  gat_aggregate<64><<<L, 256, 0, stream>>>(h1, a_s1, a_d1, m1, inv1, row_start, csr_src, b1, out1);

  // ---- GAT layer 2 (C=128, HC=512) ----
  gemm_tiled<false><<<dim3(512 / 64, L / 64), 256, 0, stream>>>(out1, Wg2, h2, L, 512, 256);
  attn_coef<<<L, 512, 2 * 512 * 4, stream>>>(h2, asrc2, adst2, a_s2, a_d2, 512, 128);
  softmax_stats<<<L, 64, 0, stream>>>(a_s2, a_d2, row_start, csr_src, m2, inv2);
  gat_aggregate<128><<<L, 512, 0, stream>>>(h2, a_s2, a_d2, m2, inv2, row_start, csr_src, b2, out2);

  // ---- pool + FC head ----
  col_sum<<<64, 512, 0, stream>>>(out2, pooled);
  fc_relu<<<1, 512, 0, stream>>>(pooled, fcW, fcb, hbuf);
  fc_out<<<1, 512, 0, stream>>>(hbuf, outW, outb, outp);
}

// Round 2
// 345.650 us; speedup vs baseline: 2.3272x; 2.3272x over previous
//
#include <hip/hip_runtime.h>
#include <hip/hip_bf16.h>

constexpr int L = 8192;          // nodes
constexpr int H = 4;             // heads (both layers)

typedef __attribute__((ext_vector_type(8))) short bf16x8;
typedef __attribute__((ext_vector_type(4))) float f32x4;

static __device__ __forceinline__ float lrelu(float e) {
  return e > 0.f ? e : 0.2f * e;
}
static __device__ __forceinline__ float b2f(unsigned short s) {
  unsigned u = ((unsigned)s) << 16;
  return __uint_as_float(u);
}

// ---------------- bf16 conversion / transpose helpers ----------------
// W [K,N] f32 -> Wt [N,Kp] bf16 (zero-pad K->Kp)
__global__ void conv_w(const float* __restrict__ W, __hip_bfloat16* __restrict__ Wt,
                       int K, int N, int Kp) {
  int i = blockIdx.x * 256 + threadIdx.x;
  if (i >= N * Kp) return;
  int n = i / Kp, k = i % Kp;
  Wt[i] = __float2bfloat16(k < K ? W[(size_t)k * N + n] : 0.f);
}

// seq [L,26] f32 -> [L,32] bf16 (zero-pad)
__global__ void conv_seq(const float* __restrict__ x, __hip_bfloat16* __restrict__ xb) {
  int i = blockIdx.x * 256 + threadIdx.x;
  int r = i >> 5, k = i & 31;
  xb[i] = __float2bfloat16(k < 26 ? x[r * 26 + k] : 0.f);
}

// ---------------- bf16 MFMA GEMM: C = op(A[M,K] @ Bt[N,K]^T) ----------------
// 64x64 tile, BK=32, 256 threads (4 waves); wave w owns rows [w*16, w*16+16)
template<bool RELU, bool OUTBF16>
__global__ __launch_bounds__(256) void gemm_mfma(
    const __hip_bfloat16* __restrict__ A, const __hip_bfloat16* __restrict__ Bt,
    void* __restrict__ Cout, int M, int N, int K) {
  __shared__ __align__(16) short As[64][40];  // pad 32->40 shorts (80B stride)
  __shared__ __align__(16) short Bs[64][40];
  int tid = threadIdx.x;
  int m0 = blockIdx.y * 64, n0 = blockIdx.x * 64;
  int w = tid >> 6, lane = tid & 63;
  f32x4 acc[4] = {};
  int lrow = tid >> 2;       // 0..63
  int lk = (tid & 3) * 8;    // 0,8,16,24

  for (int k0 = 0; k0 < K; k0 += 32) {
    *(bf16x8*)&As[lrow][lk] = *(const bf16x8*)&A[(size_t)(m0 + lrow) * K + k0 + lk];
    *(bf16x8*)&Bs[lrow][lk] = *(const bf16x8*)&Bt[(size_t)(n0 + lrow) * K + k0 + lk];
    __syncthreads();
    int r = w * 16 + (lane & 15);
    int kk = (lane >> 4) * 8;
    bf16x8 af = *(const bf16x8*)&As[r][kk];
#pragma unroll
    for (int nf = 0; nf < 4; nf++) {
      bf16x8 bfrag = *(const bf16x8*)&Bs[nf * 16 + (lane & 15)][kk];
      acc[nf] = __builtin_amdgcn_mfma_f32_16x16x32_bf16(af, bfrag, acc[nf], 0, 0, 0);
    }
    __syncthreads();
  }

  int col0 = lane & 15, r0 = w * 16 + (lane >> 4) * 4;
#pragma unroll
  for (int nf = 0; nf < 4; nf++) {
#pragma unroll
    for (int j = 0; j < 4; j++) {
      float v = acc[nf][j];
      if (RELU) v = fmaxf(v, 0.f);
      size_t idx = (size_t)(m0 + r0 + j) * N + (n0 + nf * 16 + col0);
      if (OUTBF16) ((__hip_bfloat16*)Cout)[idx] = __float2bfloat16(v);
      else ((float*)Cout)[idx] = v;
    }
  }
}

// ---------------- CSR build (counting sort by dst) ----------------
__global__ void count_deg(const int* __restrict__ ei, int E, int Etot,
                          int* __restrict__ deg) {
  int e = blockIdx.x * blockDim.x + threadIdx.x;
  if (e >= Etot) return;
  int dst = (e < E) ? ei[E + e] : (e - E);
  atomicAdd(&deg[dst], 1);
}

__global__ __launch_bounds__(1024) void scan_deg(const int* __restrict__ deg,
                                                 int* __restrict__ row_start) {
  __shared__ int part[1024];
  int tid = threadIdx.x;
  int local[8];
  int sum = 0;
#pragma unroll
  for (int j = 0; j < 8; j++) { local[j] = deg[tid * 8 + j]; sum += local[j]; }
  part[tid] = sum;
  __syncthreads();
  for (int off = 1; off < 1024; off <<= 1) {
    int v = part[tid];
    int add = (tid >= off) ? part[tid - off] : 0;
    __syncthreads();
    part[tid] = v + add;
    __syncthreads();
  }
  int base = part[tid] - sum;  // exclusive prefix
#pragma unroll
  for (int j = 0; j < 8; j++) { row_start[tid * 8 + j] = base; base += local[j]; }
  if (tid == 1023) row_start[L] = part[1023];
}

__global__ void scatter_edges(const int* __restrict__ ei, int E, int Etot,
                              const int* __restrict__ row_start,
                              int* __restrict__ cursor, int* __restrict__ csr_src) {
  int e = blockIdx.x * blockDim.x + threadIdx.x;
  if (e >= Etot) return;
  int srcv, dstv;
  if (e < E) { srcv = ei[e]; dstv = ei[E + e]; } else { srcv = dstv = e - E; }
  int pos = row_start[dstv] + atomicAdd(&cursor[dstv], 1);
  csr_src[pos] = srcv;
}

// ---------------- attention coefficients a_s, a_d per node/head ----------------
__global__ void attn_coef(const __hip_bfloat16* __restrict__ hfeat,
                          const float* __restrict__ asrc, const float* __restrict__ adst,
                          float* __restrict__ a_s, float* __restrict__ a_d,
                          int HC, int C) {
  extern __shared__ float red[];  // 2*HC floats
  int n = blockIdx.x, tid = threadIdx.x;
  float hv = __bfloat162float(hfeat[(size_t)n * HC + tid]);
  red[tid] = hv * asrc[tid];
  red[HC + tid] = hv * adst[tid];
  __syncthreads();
  for (int s = C >> 1; s > 0; s >>= 1) {
    if ((tid & (C - 1)) < s) {
      red[tid] += red[tid + s];
      red[HC + tid] += red[HC + tid + s];
    }
    __syncthreads();
  }
  if ((tid & (C - 1)) == 0) {
    int h = tid / C;
    a_s[n * H + h] = red[tid];
    a_d[n * H + h] = red[HC + tid];
  }
}

// ---------------- per-node softmax + per-edge alpha (one wave per node) --------
__global__ __launch_bounds__(64) void softmax_alpha(
    const float* __restrict__ a_s, const float* __restrict__ a_d,
    const int* __restrict__ row_start, const int* __restrict__ csr_src,
    float* __restrict__ alpha) {
  int n = blockIdx.x, lane = threadIdx.x;
  int rs = row_start[n], re = row_start[n + 1];
  const float4 adn4 = *reinterpret_cast<const float4*>(&a_d[n * H]);
  float adn[4] = {adn4.x, adn4.y, adn4.z, adn4.w};
  float m[4], s[4];
#pragma unroll
  for (int h = 0; h < 4; h++) { m[h] = -1e30f; s[h] = 0.f; }
  for (int i = rs + lane; i < re; i += 64) {
    int sr = csr_src[i];
    const float4 as4 = *reinterpret_cast<const float4*>(&a_s[sr * H]);
    float asv[4] = {as4.x, as4.y, as4.z, as4.w};
#pragma unroll
    for (int h = 0; h < 4; h++) {
      float e = lrelu(asv[h] + adn[h]);
      if (e > m[h]) { s[h] = s[h] * __expf(m[h] - e) + 1.f; m[h] = e; }
      else s[h] += __expf(e - m[h]);
    }
  }
#pragma unroll
  for (int off = 32; off > 0; off >>= 1) {
#pragma unroll
    for (int h = 0; h < 4; h++) {
      float om = __shfl_xor(m[h], off);
      float os = __shfl_xor(s[h], off);
      float M = fmaxf(m[h], om);
      s[h] = s[h] * __expf(m[h] - M) + os * __expf(om - M);
      m[h] = M;
    }
  }
  float inv[4];
#pragma unroll
  for (int h = 0; h < 4; h++) inv[h] = 1.f / (s[h] + 1e-16f);
  // second sweep: write alpha per CSR slot
  for (int i = rs + lane; i < re; i += 64) {
    int sr = csr_src[i];
    const float4 as4 = *reinterpret_cast<const float4*>(&a_s[sr * H]);
    float asv[4] = {as4.x, as4.y, as4.z, as4.w};
    float4 out;
    out.x = __expf(lrelu(asv[0] + adn[0]) - m[0]) * inv[0];
    out.y = __expf(lrelu(asv[1] + adn[1]) - m[1]) * inv[1];
    out.z = __expf(lrelu(asv[2] + adn[2]) - m[2]) * inv[2];
    out.w = __expf(lrelu(asv[3] + adn[3]) - m[3]) * inv[3];
    *reinterpret_cast<float4*>(&alpha[(size_t)i * 4]) = out;
  }
}

// ---------------- weighted aggregation + bias + relu ----------------
// block = HC/4 threads, each owns 4 adjacent channels; one node per block
template<int C, bool OUTBF16>
__global__ void gat_aggregate(
    const __hip_bfloat16* __restrict__ hfeat, const float* __restrict__ alpha,
    const int* __restrict__ row_start, const int* __restrict__ csr_src,
    const float* __restrict__ bias, void* __restrict__ out) {
  constexpr int HC = H * C;
  constexpr int T = HC / 4;
  int n = blockIdx.x, tid = threadIdx.x;
  int c0 = tid * 4;
  int hh = c0 / C;
  int rs = row_start[n], re = row_start[n + 1];
  float acc[4] = {0.f, 0.f, 0.f, 0.f};
  __shared__ int s_src[64];
  __shared__ float4 s_al[64];
  for (int base = rs; base < re; base += 64) {
    int cnt = min(64, re - base);
    __syncthreads();
    for (int j = tid; j < cnt; j += T) {
      s_src[j] = csr_src[base + j];
      s_al[j] = *reinterpret_cast<const float4*>(&alpha[(size_t)(base + j) * 4]);
    }
    __syncthreads();
#pragma unroll 4
    for (int j = 0; j < cnt; j++) {
      int sr = s_src[j];
      float al = reinterpret_cast<const float*>(&s_al[j])[hh];
      ushort4 v = *reinterpret_cast<const ushort4*>(&hfeat[(size_t)sr * HC + c0]);
      acc[0] = fmaf(al, b2f(v.x), acc[0]);
      acc[1] = fmaf(al, b2f(v.y), acc[1]);
      acc[2] = fmaf(al, b2f(v.z), acc[2]);
      acc[3] = fmaf(al, b2f(v.w), acc[3]);
    }
  }
#pragma unroll
  for (int k = 0; k < 4; k++) acc[k] = fmaxf(acc[k] + bias[c0 + k], 0.f);
  if (OUTBF16) {
    __hip_bfloat16* o = (__hip_bfloat16*)out;
#pragma unroll
    for (int k = 0; k < 4; k++) o[(size_t)n * HC + c0 + k] = __float2bfloat16(acc[k]);
  } else {
    float4 o4 = {acc[0], acc[1], acc[2], acc[3]};
    *reinterpret_cast<float4*>(&((float*)out)[(size_t)n * HC + c0]) = o4;
  }
}

// ---------------- pooled column sum ----------------
__global__ __launch_bounds__(512) void col_sum(const float* __restrict__ x,
                                               float* __restrict__ pooled) {
  int t = threadIdx.x;
  float acc = 0.f;
  for (int r = blockIdx.x; r < L; r += gridDim.x) acc += x[(size_t)r * 512 + t];
  atomicAdd(&pooled[t], acc);
}

// ---------------- small FC layers ----------------
__global__ __launch_bounds__(512) void fc_relu(const float* __restrict__ in,
                                               const float* __restrict__ W,
                                               const float* __restrict__ b,
                                               float* __restrict__ out) {
  __shared__ float pv[512];
  int t = threadIdx.x;
  pv[t] = in[t];
  __syncthreads();
  float acc = 0.f;
  for (int k = 0; k < 512; k++) acc = fmaf(pv[k], W[k * 512 + t], acc);
  out[t] = fmaxf(acc + b[t], 0.f);
}

__global__ __launch_bounds__(512) void fc_out(const float* __restrict__ hin,
                                              const float* __restrict__ W,
                                              const float* __restrict__ b,
                                              float* __restrict__ out) {
  __shared__ float pv[512];
  int t = threadIdx.x;
  pv[t] = hin[t];
  __syncthreads();
  if (t < 489) {
    float acc = 0.f;
    for (int k = 0; k < 512; k++) acc = fmaf(pv[k], W[k * 489 + t], acc);
    out[t] = acc + b[t];
  }
}

extern "C" void kernel_launch(void* const* d_in, const int* in_sizes, int n_in,
                              void* d_out, int out_size, void* d_ws, size_t ws_size,
                              hipStream_t stream) {
  const float* seq   = (const float*)d_in[0];
  const int*   ei    = (const int*)d_in[1];
  const float* W1    = (const float*)d_in[2];
  const float* W2    = (const float*)d_in[3];
  const float* Wg1   = (const float*)d_in[4];
  const float* asrc1 = (const float*)d_in[5];
  const float* adst1 = (const float*)d_in[6];
  const float* b1    = (const float*)d_in[7];
  const float* Wg2   = (const float*)d_in[8];
  const float* asrc2 = (const float*)d_in[9];
  const float* adst2 = (const float*)d_in[10];
  const float* b2    = (const float*)d_in[11];
  const float* fcW   = (const float*)d_in[12];
  const float* fcb   = (const float*)d_in[13];
  const float* outW  = (const float*)d_in[14];
  const float* outb  = (const float*)d_in[15];
  float* outp = (float*)d_out;

  const int E = in_sizes[1] / 2;      // 524288
  const int Etot = E + L;             // + self loops

  // ---- workspace layout (bytes) ----
  char* ws = (char*)d_ws;
  __hip_bfloat16* mlp1 = (__hip_bfloat16*)(ws + 0);          // [L,1024] bf16 16MB
  float*          out2 = (float*)(ws + 0);                   // [L,512] f32 16MB (after mlp1 dead)
  __hip_bfloat16* h2   = (__hip_bfloat16*)(ws + (16u << 20)); // [L,512] bf16 8MB
  __hip_bfloat16* x0   = (__hip_bfloat16*)(ws + (24u << 20)); // [L,256] bf16 4MB
  __hip_bfloat16* h1   = (__hip_bfloat16*)(ws + (28u << 20)); // [L,256] bf16 4MB
  __hip_bfloat16* out1 = (__hip_bfloat16*)(ws + (32u << 20)); // [L,256] bf16 4MB
  size_t off = (36u << 20);
  float* alpha = (float*)(ws + off); off += (size_t)Etot * 16;         // 8.5MB
  off = (off + 255) & ~(size_t)255;
  __hip_bfloat16* xb   = (__hip_bfloat16*)(ws + off); off += (size_t)L * 32 * 2;    // 512KB
  __hip_bfloat16* W1t  = (__hip_bfloat16*)(ws + off); off += (size_t)1024 * 32 * 2; // 64KB
  __hip_bfloat16* W2t  = (__hip_bfloat16*)(ws + off); off += (size_t)256 * 1024 * 2;// 512KB
  __hip_bfloat16* Wg1t = (__hip_bfloat16*)(ws + off); off += (size_t)256 * 256 * 2; // 128KB
  __hip_bfloat16* Wg2t = (__hip_bfloat16*)(ws + off); off += (size_t)512 * 256 * 2; // 256KB
  int* csr_src   = (int*)(ws + off); off += (size_t)Etot * 4;
  off = (off + 255) & ~(size_t)255;
  int* row_start = (int*)(ws + off); off += (size_t)(L + 1) * 4;
  off = (off + 255) & ~(size_t)255;
  int* deg    = (int*)(ws + off); off += (size_t)L * 4;
  int* cursor = (int*)(ws + off); off += (size_t)L * 4;   // adjacent to deg
  float* a_s1 = (float*)(ws + off); off += (size_t)L * H * 4;
  float* a_d1 = (float*)(ws + off); off += (size_t)L * H * 4;
  float* a_s2 = (float*)(ws + off); off += (size_t)L * H * 4;
  float* a_d2 = (float*)(ws + off); off += (size_t)L * H * 4;
  float* pooled = (float*)(ws + off); off += 512 * 4;
  float* hbuf   = (float*)(ws + off); off += 512 * 4;

  // ---- zero accumulators ----
  hipMemsetAsync(deg, 0, (size_t)L * 8, stream);        // deg + cursor
  hipMemsetAsync(pooled, 0, 512 * 4, stream);

  // ---- convert inputs/weights to bf16 (transposed weights) ----
  conv_seq<<<(L * 32) / 256, 256, 0, stream>>>(seq, xb);
  conv_w<<<(1024 * 32 + 255) / 256, 256, 0, stream>>>(W1, W1t, 26, 1024, 32);
  conv_w<<<(256 * 1024 + 255) / 256, 256, 0, stream>>>(W2, W2t, 1024, 256, 1024);
  conv_w<<<(256 * 256 + 255) / 256, 256, 0, stream>>>(Wg1, Wg1t, 256, 256, 256);
  conv_w<<<(512 * 256 + 255) / 256, 256, 0, stream>>>(Wg2, Wg2t, 256, 512, 256);

  // ---- CSR build ----
  int eb = (Etot + 255) / 256;
  count_deg<<<eb, 256, 0, stream>>>(ei, E, Etot, deg);
  scan_deg<<<1, 1024, 0, stream>>>(deg, row_start);
  scatter_edges<<<eb, 256, 0, stream>>>(ei, E, Etot, row_start, cursor, csr_src);

  // ---- input MLP (bf16 MFMA) ----
  gemm_mfma<true, true><<<dim3(1024 / 64, L / 64), 256, 0, stream>>>(xb, W1t, mlp1, L, 1024, 32);
  gemm_mfma<false, true><<<dim3(256 / 64, L / 64), 256, 0, stream>>>(mlp1, W2t, x0, L, 256, 1024);

  // ---- GAT layer 1 (C=64, HC=256) ----
  gemm_mfma<false, true><<<dim3(256 / 64, L / 64), 256, 0, stream>>>(x0, Wg1t, h1, L, 256, 256);
  attn_coef<<<L, 256, 2 * 256 * 4, stream>>>(h1, asrc1, adst1, a_s1, a_d1, 256, 64);
  softmax_alpha<<<L, 64, 0, stream>>>(a_s1, a_d1, row_start, csr_src, alpha);
  gat_aggregate<64, true><<<L, 64, 0, stream>>>(h1, alpha, row_start, csr_src, b1, out1);

  // ---- GAT layer 2 (C=128, HC=512) ----
  gemm_mfma<false, true><<<dim3(512 / 64, L / 64), 256, 0, stream>>>(out1, Wg2t, h2, L, 512, 256);
  attn_coef<<<L, 512, 2 * 512 * 4, stream>>>(h2, asrc2, adst2, a_s2, a_d2, 512, 128);
  softmax_alpha<<<L, 64, 0, stream>>>(a_s2, a_d2, row_start, csr_src, alpha);
  gat_aggregate<128, false><<<L, 128, 0, stream>>>(h2, alpha, row_start, csr_src, b2, out2);

  // ---- pool + FC head ----
  col_sum<<<64, 512, 0, stream>>>(out2, pooled);
  fc_relu<<<1, 512, 0, stream>>>(pooled, fcW, fcb, hbuf);
  fc_out<<<1, 512, 0, stream>>>(hbuf, outW, outb, outp);
}

// Round 3
// 298.938 us; speedup vs baseline: 2.6908x; 1.1563x over previous
//
#include <hip/hip_runtime.h>
#include <hip/hip_bf16.h>

constexpr int L = 8192;          // nodes
constexpr int H = 4;             // heads (both layers)

typedef __attribute__((ext_vector_type(8))) short bf16x8;
typedef __attribute__((ext_vector_type(8))) unsigned short u16x8;
typedef __attribute__((ext_vector_type(4))) float f32x4;

static __device__ __forceinline__ float lrelu(float e) {
  return e > 0.f ? e : 0.2f * e;
}
static __device__ __forceinline__ float b2f(unsigned short s) {
  return __uint_as_float(((unsigned)s) << 16);
}
static __device__ __forceinline__ unsigned short f2b(float f) {
  __hip_bfloat16 h = __float2bfloat16(f);
  return *reinterpret_cast<unsigned short*>(&h);
}
static __device__ __forceinline__ float readlane_f(float v, int l) {
  return __uint_as_float(__builtin_amdgcn_readlane(__float_as_uint(v), l));
}

// ================= merged conversion / transpose / degree-count =================
// segments (element counts):
// 0: xb     262144   seq [L,26]f32 -> [L,32]bf16 pad
// 1: W1t    32768    W1 [26,1024] -> [1024,32]bf16 pad
// 2: W2t    262144   W2 [1024,256] -> [256,1024]bf16
// 3: Wg1t   65536    Wg1 [256,256] -> [256,256]bf16
// 4: Wg2t   131072   Wg2 [256,512] -> [512,256]bf16
// 5: fcWt   262144   fcW [512,512]f32 -> [512,512]f32 transpose
// 6: outWt  262144   outW [512,489]f32 -> [512,512]f32 transpose+pad
// 7: deg    Etot     count_deg
__global__ void conv_all(const float* __restrict__ seq, const float* __restrict__ W1,
                         const float* __restrict__ W2, const float* __restrict__ Wg1,
                         const float* __restrict__ Wg2, const float* __restrict__ fcW,
                         const float* __restrict__ outW, const int* __restrict__ ei,
                         int E, int Etot,
                         __hip_bfloat16* __restrict__ xb, __hip_bfloat16* __restrict__ W1t,
                         __hip_bfloat16* __restrict__ W2t, __hip_bfloat16* __restrict__ Wg1t,
                         __hip_bfloat16* __restrict__ Wg2t, float* __restrict__ fcWt,
                         float* __restrict__ outWt, int* __restrict__ deg) {
  int i = blockIdx.x * 256 + threadIdx.x;
  if (i < 262144) { int r = i >> 5, k = i & 31;
    xb[i] = __float2bfloat16(k < 26 ? seq[r * 26 + k] : 0.f); return; }
  i -= 262144;
  if (i < 32768) { int n = i >> 5, k = i & 31;
    W1t[i] = __float2bfloat16(k < 26 ? W1[k * 1024 + n] : 0.f); return; }
  i -= 32768;
  if (i < 262144) { int n = i >> 10, k = i & 1023;
    W2t[i] = __float2bfloat16(W2[k * 256 + n]); return; }
  i -= 262144;
  if (i < 65536) { int n = i >> 8, k = i & 255;
    Wg1t[i] = __float2bfloat16(Wg1[k * 256 + n]); return; }
  i -= 65536;
  if (i < 131072) { int n = i >> 8, k = i & 255;
    Wg2t[i] = __float2bfloat16(Wg2[k * 512 + n]); return; }
  i -= 131072;
  if (i < 262144) { int o = i >> 9, k = i & 511;
    fcWt[i] = fcW[k * 512 + o]; return; }
  i -= 262144;
  if (i < 262144) { int o = i >> 9, k = i & 511;
    outWt[i] = (o < 489) ? outW[k * 489 + o] : 0.f; return; }
  i -= 262144;
  if (i < Etot) {
    int dst = (i < E) ? ei[E + i] : (i - E);
    atomicAdd(&deg[dst], 1);
  }
}

// wa[k][0..3]=sum_c Wg[k,h*C+c]*asrc[h,c]; wa[k][4..7]=same with adst
__global__ void calc_wa(const float* __restrict__ Wg1, const float* __restrict__ as1,
                        const float* __restrict__ ad1, const float* __restrict__ Wg2,
                        const float* __restrict__ as2, const float* __restrict__ ad2,
                        float* __restrict__ wa1, float* __restrict__ wa2) {
  int t = blockIdx.x * 256 + threadIdx.x;
  if (t < 2048) {
    int k = t >> 3, o = t & 7, h = o & 3;
    const float* av = (o < 4) ? as1 : ad1;
    float s = 0.f;
    for (int c = 0; c < 64; c++) s += Wg1[k * 256 + h * 64 + c] * av[h * 64 + c];
    wa1[k * 8 + o] = s;
  } else if (t < 4096) {
    int tt = t - 2048;
    int k = tt >> 3, o = tt & 7, h = o & 3;
    const float* av = (o < 4) ? as2 : ad2;
    float s = 0.f;
    for (int c = 0; c < 128; c++) s += Wg2[k * 512 + h * 128 + c] * av[h * 128 + c];
    wa2[k * 8 + o] = s;
  }
}

// a_sd[L][8] = x[L,256](bf16) @ wa[256,8](f32)
__global__ __launch_bounds__(256) void calc_asd(
    const __hip_bfloat16* __restrict__ x, const float* __restrict__ wa,
    float* __restrict__ a_sd) {
  __shared__ float swa[256][8];
  __shared__ float red[64][4][8];
  int t = threadIdx.x;
  for (int i = t; i < 2048; i += 256) swa[i >> 3][i & 7] = wa[i];
  __syncthreads();
  int rl = t >> 2, q = t & 3;
  int row = blockIdx.x * 64 + rl;
  float p[8] = {};
  const __hip_bfloat16* xr = &x[(size_t)row * 256 + q * 64];
  for (int kk = 0; kk < 64; kk += 8) {
    u16x8 v = *(const u16x8*)&xr[kk];
#pragma unroll
    for (int e = 0; e < 8; e++) {
      float xv = b2f(v[e]);
      int k = q * 64 + kk + e;
      float4 w0 = *(const float4*)&swa[k][0];
      float4 w1 = *(const float4*)&swa[k][4];
      p[0] = fmaf(xv, w0.x, p[0]); p[1] = fmaf(xv, w0.y, p[1]);
      p[2] = fmaf(xv, w0.z, p[2]); p[3] = fmaf(xv, w0.w, p[3]);
      p[4] = fmaf(xv, w1.x, p[4]); p[5] = fmaf(xv, w1.y, p[5]);
      p[6] = fmaf(xv, w1.z, p[6]); p[7] = fmaf(xv, w1.w, p[7]);
    }
  }
#pragma unroll
  for (int o = 0; o < 8; o++) red[rl][q][o] = p[o];
  __syncthreads();
  if (q == 0) {
#pragma unroll
    for (int o = 0; o < 8; o++)
      a_sd[(size_t)row * 8 + o] =
          red[rl][0][o] + red[rl][1][o] + red[rl][2][o] + red[rl][3][o];
  }
}

// ================= bf16 MFMA GEMM: C = op(A[M,K] @ Bt[N,K]^T) =================
template<int BK, bool RELU, bool OUTBF16>
__global__ __launch_bounds__(256) void gemm_mfma(
    const __hip_bfloat16* __restrict__ A, const __hip_bfloat16* __restrict__ Bt,
    void* __restrict__ Cout, int M, int N, int K) {
  __shared__ __align__(16) short As[64][BK + 8];
  __shared__ __align__(16) short Bs[64][BK + 8];
  int tid = threadIdx.x;
  int m0 = blockIdx.y * 64, n0 = blockIdx.x * 64;
  int w = tid >> 6, lane = tid & 63;
  f32x4 acc[4] = {};
  int lrow = tid >> 2;
  int lk = (tid & 3) * 8;
  for (int k0 = 0; k0 < K; k0 += BK) {
#pragma unroll
    for (int lc = 0; lc < BK; lc += 32) {
      *(bf16x8*)&As[lrow][lk + lc] = *(const bf16x8*)&A[(size_t)(m0 + lrow) * K + k0 + lk + lc];
      *(bf16x8*)&Bs[lrow][lk + lc] = *(const bf16x8*)&Bt[(size_t)(n0 + lrow) * K + k0 + lk + lc];
    }
    __syncthreads();
    int r = w * 16 + (lane & 15);
    int kk = (lane >> 4) * 8;
#pragma unroll
    for (int ks = 0; ks < BK; ks += 32) {
      bf16x8 af = *(const bf16x8*)&As[r][kk + ks];
#pragma unroll
      for (int nf = 0; nf < 4; nf++) {
        bf16x8 bfrag = *(const bf16x8*)&Bs[nf * 16 + (lane & 15)][kk + ks];
        acc[nf] = __builtin_amdgcn_mfma_f32_16x16x32_bf16(af, bfrag, acc[nf], 0, 0, 0);
      }
    }
    __syncthreads();
  }
  int col0 = lane & 15, r0 = w * 16 + (lane >> 4) * 4;
#pragma unroll
  for (int nf = 0; nf < 4; nf++) {
#pragma unroll
    for (int j = 0; j < 4; j++) {
      float v = acc[nf][j];
      if (RELU) v = fmaxf(v, 0.f);
      size_t idx = (size_t)(m0 + r0 + j) * N + (n0 + nf * 16 + col0);
      if (OUTBF16) ((__hip_bfloat16*)Cout)[idx] = __float2bfloat16(v);
      else ((float*)Cout)[idx] = v;
    }
  }
}

// ================= CSR build =================
__global__ __launch_bounds__(1024) void scan_deg(const int* __restrict__ deg,
                                                 int* __restrict__ row_start,
                                                 float* __restrict__ pooled) {
  __shared__ int part[1024];
  int tid = threadIdx.x;
  if (tid < 512) pooled[tid] = 0.f;
  int local[8];
  int sum = 0;
#pragma unroll
  for (int j = 0; j < 8; j++) { local[j] = deg[tid * 8 + j]; sum += local[j]; }
  part[tid] = sum;
  __syncthreads();
  for (int off = 1; off < 1024; off <<= 1) {
    int v = part[tid];
    int add = (tid >= off) ? part[tid - off] : 0;
    __syncthreads();
    part[tid] = v + add;
    __syncthreads();
  }
  int base = part[tid] - sum;
#pragma unroll
  for (int j = 0; j < 8; j++) { row_start[tid * 8 + j] = base; base += local[j]; }
  if (tid == 1023) row_start[L] = part[1023];
}

__global__ void scatter_edges(const int* __restrict__ ei, int E, int Etot,
                              const int* __restrict__ row_start,
                              int* __restrict__ cursor, int* __restrict__ csr_src) {
  int e = blockIdx.x * blockDim.x + threadIdx.x;
  if (e >= Etot) return;
  int srcv, dstv;
  if (e < E) { srcv = ei[e]; dstv = ei[E + e]; } else { srcv = dstv = e - E; }
  int pos = row_start[dstv] + atomicAdd(&cursor[dstv], 1);
  csr_src[pos] = srcv;
}

// ================= fused softmax + aggregate: one wave per node =================
template<int C, bool OUTBF16>
__global__ __launch_bounds__(256) void gat_fused(
    const __hip_bfloat16* __restrict__ hfeat, const float* __restrict__ a_sd,
    const int* __restrict__ row_start, const int* __restrict__ csr_src,
    const float* __restrict__ bias, void* __restrict__ out) {
  constexpr int HC = 4 * C;
  constexpr int VPT = HC / 64;   // 4 (C=64) or 8 (C=128)
  int wid = threadIdx.x >> 6, lane = threadIdx.x & 63;
  int n = blockIdx.x * 4 + wid;
  int c0 = lane * VPT;
  int hh = c0 / C;
  int rs = row_start[n], re = row_start[n + 1];
  float4 ad4 = *(const float4*)&a_sd[(size_t)n * 8 + 4];
  float adn[4] = {ad4.x, ad4.y, ad4.z, ad4.w};

  // ---- sweep 1: per-head max + denom (online, lane-strided) ----
  float m[4] = {-1e30f, -1e30f, -1e30f, -1e30f}, s[4] = {0.f, 0.f, 0.f, 0.f};
  for (int i = rs + lane; i < re; i += 64) {
    int sr = csr_src[i];
    float4 as4 = *(const float4*)&a_sd[(size_t)sr * 8];
    float ev[4] = {as4.x + adn[0], as4.y + adn[1], as4.z + adn[2], as4.w + adn[3]};
#pragma unroll
    for (int h = 0; h < 4; h++) {
      float e = lrelu(ev[h]);
      float nm = fmaxf(m[h], e);
      s[h] = s[h] * __expf(m[h] - nm) + __expf(e - nm);
      m[h] = nm;
    }
  }
#pragma unroll
  for (int off = 32; off > 0; off >>= 1) {
#pragma unroll
    for (int h = 0; h < 4; h++) {
      float om = __shfl_xor(m[h], off);
      float os = __shfl_xor(s[h], off);
      float M = fmaxf(m[h], om);
      s[h] = s[h] * __expf(m[h] - M) + os * __expf(om - M);
      m[h] = M;
    }
  }
  float inv[4];
#pragma unroll
  for (int h = 0; h < 4; h++) inv[h] = 1.f / (s[h] + 1e-16f);

  // ---- sweep 2: alpha + gather-FMA, 64-edge chunks, readlane broadcast ----
  float acc[VPT] = {};
  auto edge = [&](int j, int srcv, const float* al) {
    int sr = __builtin_amdgcn_readlane(srcv, j);
    float a0 = readlane_f(al[0], j), a1 = readlane_f(al[1], j);
    float a2 = readlane_f(al[2], j), a3 = readlane_f(al[3], j);
    float av = hh == 0 ? a0 : hh == 1 ? a1 : hh == 2 ? a2 : a3;
    const unsigned short* hp = (const unsigned short*)&hfeat[(size_t)sr * HC + c0];
    if constexpr (VPT == 8) {
      u16x8 v = *(const u16x8*)hp;
#pragma unroll
      for (int k = 0; k < 8; k++) acc[k] = fmaf(av, b2f(v[k]), acc[k]);
    } else {
      ushort4 v = *(const ushort4*)hp;
      acc[0] = fmaf(av, b2f(v.x), acc[0]);
      acc[1] = fmaf(av, b2f(v.y), acc[1]);
      acc[2] = fmaf(av, b2f(v.z), acc[2]);
      acc[3] = fmaf(av, b2f(v.w), acc[3]);
    }
  };
  for (int base = rs; base < re; base += 64) {
    int cnt = min(64, re - base);
    int srcv = 0;
    float al[4] = {0.f, 0.f, 0.f, 0.f};
    if (lane < cnt) {
      srcv = csr_src[base + lane];
      float4 as4 = *(const float4*)&a_sd[(size_t)srcv * 8];
      al[0] = __expf(lrelu(as4.x + adn[0]) - m[0]) * inv[0];
      al[1] = __expf(lrelu(as4.y + adn[1]) - m[1]) * inv[1];
      al[2] = __expf(lrelu(as4.z + adn[2]) - m[2]) * inv[2];
      al[3] = __expf(lrelu(as4.w + adn[3]) - m[3]) * inv[3];
    }
    int j = 0;
    for (; j + 4 <= cnt; j += 4) {
      edge(j, srcv, al); edge(j + 1, srcv, al);
      edge(j + 2, srcv, al); edge(j + 3, srcv, al);
    }
    for (; j < cnt; j++) edge(j, srcv, al);
  }

  // ---- epilogue ----
#pragma unroll
  for (int k = 0; k < VPT; k++) acc[k] = fmaxf(acc[k] + bias[c0 + k], 0.f);
  if constexpr (OUTBF16) {
    if constexpr (VPT == 8) {
      u16x8 ov;
#pragma unroll
      for (int k = 0; k < 8; k++) ov[k] = f2b(acc[k]);
      *(u16x8*)((unsigned short*)out + (size_t)n * HC + c0) = ov;
    } else {
      ushort4 ov = {f2b(acc[0]), f2b(acc[1]), f2b(acc[2]), f2b(acc[3])};
      *(ushort4*)((unsigned short*)out + (size_t)n * HC + c0) = ov;
    }
  } else {
#pragma unroll
    for (int k = 0; k < VPT; k++) ((float*)out)[(size_t)n * HC + c0 + k] = acc[k];
  }
}

// ================= pooled column sum (bf16 in, f32 atomic out) =================
__global__ __launch_bounds__(512) void col_sum_bf16(const __hip_bfloat16* __restrict__ x,
                                                    float* __restrict__ pooled) {
  int t = threadIdx.x;
  float acc = 0.f;
  for (int r = blockIdx.x; r < L; r += 64)
    acc += b2f(*(const unsigned short*)&x[(size_t)r * 512 + t]);
  atomicAdd(&pooled[t], acc);
}

// ================= FC head (pre-transposed f32 weights) =================
__global__ __launch_bounds__(256) void fc1(const float* __restrict__ pooled,
                                           const float* __restrict__ Wt,
                                           const float* __restrict__ b,
                                           float* __restrict__ out) {
  __shared__ float pv[512];
  __shared__ float red[256];
  int t = threadIdx.x;
  pv[t] = pooled[t]; pv[t + 256] = pooled[t + 256];
  __syncthreads();
  int ol = t >> 4;
  int o = blockIdx.x * 16 + ol;
  int ks = (t & 15) * 32;
  float p = 0.f;
  const float* wr = &Wt[(size_t)o * 512 + ks];
#pragma unroll
  for (int kk = 0; kk < 32; kk++) p = fmaf(pv[ks + kk], wr[kk], p);
  red[t] = p;
  __syncthreads();
  if ((t & 15) == 0) {
    float s2 = 0.f;
#pragma unroll
    for (int i = 0; i < 16; i++) s2 += red[ol * 16 + i];
    out[o] = fmaxf(s2 + b[o], 0.f);
  }
}

__global__ __launch_bounds__(256) void fc2(const float* __restrict__ h,
                                           const float* __restrict__ Wt,
                                           const float* __restrict__ outb,
                                           float* __restrict__ out) {
  __shared__ float pv[512];
  __shared__ float red[256];
  int t = threadIdx.x;
  pv[t] = h[t]; pv[t + 256] = h[t + 256];
  __syncthreads();
  int ol = t >> 4;
  int o = blockIdx.x * 16 + ol;
  int ks = (t & 15) * 32;
  float p = 0.f;
  const float* wr = &Wt[(size_t)o * 512 + ks];
#pragma unroll
  for (int kk = 0; kk < 32; kk++) p = fmaf(pv[ks + kk], wr[kk], p);
  red[t] = p;
  __syncthreads();
  if ((t & 15) == 0 && o < 489) {
    float s2 = 0.f;
#pragma unroll
    for (int i = 0; i < 16; i++) s2 += red[ol * 16 + i];
    out[o] = s2 + outb[o];
  }
}

extern "C" void kernel_launch(void* const* d_in, const int* in_sizes, int n_in,
                              void* d_out, int out_size, void* d_ws, size_t ws_size,
                              hipStream_t stream) {
  const float* seq   = (const float*)d_in[0];
  const int*   ei    = (const int*)d_in[1];
  const float* W1    = (const float*)d_in[2];
  const float* W2    = (const float*)d_in[3];
  const float* Wg1   = (const float*)d_in[4];
  const float* asrc1 = (const float*)d_in[5];
  const float* adst1 = (const float*)d_in[6];
  const float* b1    = (const float*)d_in[7];
  const float* Wg2   = (const float*)d_in[8];
  const float* asrc2 = (const float*)d_in[9];
  const float* adst2 = (const float*)d_in[10];
  const float* b2    = (const float*)d_in[11];
  const float* fcW   = (const float*)d_in[12];
  const float* fcb   = (const float*)d_in[13];
  const float* outW  = (const float*)d_in[14];
  const float* outb  = (const float*)d_in[15];
  float* outp = (float*)d_out;

  const int E = in_sizes[1] / 2;      // 524288
  const int Etot = E + L;             // + self loops

  // ---- workspace layout ----
  char* ws = (char*)d_ws;
  __hip_bfloat16* mlp1 = (__hip_bfloat16*)(ws + 0);           // [L,1024] 16MB
  __hip_bfloat16* out2 = (__hip_bfloat16*)(ws + 0);           // [L,512] 8MB (mlp1 dead)
  __hip_bfloat16* h2   = (__hip_bfloat16*)(ws + (16u << 20)); // [L,512] 8MB
  __hip_bfloat16* x0   = (__hip_bfloat16*)(ws + (24u << 20)); // [L,256] 4MB
  __hip_bfloat16* h1   = (__hip_bfloat16*)(ws + (28u << 20)); // [L,256] 4MB
  __hip_bfloat16* out1 = (__hip_bfloat16*)(ws + (32u << 20)); // [L,256] 4MB
  size_t off = (36u << 20);
  __hip_bfloat16* xb   = (__hip_bfloat16*)(ws + off); off += (size_t)L * 32 * 2;
  __hip_bfloat16* W1t  = (__hip_bfloat16*)(ws + off); off += (size_t)1024 * 32 * 2;
  __hip_bfloat16* W2t  = (__hip_bfloat16*)(ws + off); off += (size_t)256 * 1024 * 2;
  __hip_bfloat16* Wg1t = (__hip_bfloat16*)(ws + off); off += (size_t)256 * 256 * 2;
  __hip_bfloat16* Wg2t = (__hip_bfloat16*)(ws + off); off += (size_t)512 * 256 * 2;
  float* fcWt  = (float*)(ws + off); off += (size_t)512 * 512 * 4;
  float* outWt = (float*)(ws + off); off += (size_t)512 * 512 * 4;
  int* csr_src = (int*)(ws + off); off += (size_t)Etot * 4;
  off = (off + 255) & ~(size_t)255;
  int* row_start = (int*)(ws + off); off += (size_t)(L + 1) * 4;
  off = (off + 255) & ~(size_t)255;
  int* deg    = (int*)(ws + off); off += (size_t)L * 4;
  int* cursor = (int*)(ws + off); off += (size_t)L * 4;   // adjacent to deg
  float* a_sd1 = (float*)(ws + off); off += (size_t)L * 8 * 4;
  float* a_sd2 = (float*)(ws + off); off += (size_t)L * 8 * 4;
  float* wa1 = (float*)(ws + off); off += 2048 * 4;
  float* wa2 = (float*)(ws + off); off += 2048 * 4;
  float* pooled = (float*)(ws + off); off += 512 * 4;
  float* hbuf   = (float*)(ws + off); off += 512 * 4;

  // ---- zero deg+cursor (adjacent) ----
  hipMemsetAsync(deg, 0, (size_t)L * 8, stream);

  // ---- merged conversions + degree count ----
  int convN = 1277952 + Etot;
  conv_all<<<(convN + 255) / 256, 256, 0, stream>>>(
      seq, W1, W2, Wg1, Wg2, fcW, outW, ei, E, Etot,
      xb, W1t, W2t, Wg1t, Wg2t, fcWt, outWt, deg);
  calc_wa<<<16, 256, 0, stream>>>(Wg1, asrc1, adst1, Wg2, asrc2, adst2, wa1, wa2);

  // ---- CSR ----
  scan_deg<<<1, 1024, 0, stream>>>(deg, row_start, pooled);
  scatter_edges<<<(Etot + 255) / 256, 256, 0, stream>>>(ei, E, Etot, row_start, cursor, csr_src);

  // ---- input MLP ----
  gemm_mfma<32, true, true><<<dim3(16, 128), 256, 0, stream>>>(xb, W1t, mlp1, L, 1024, 32);
  gemm_mfma<64, false, true><<<dim3(4, 128), 256, 0, stream>>>(mlp1, W2t, x0, L, 256, 1024);

  // ---- GAT layer 1 (C=64) ----
  calc_asd<<<128, 256, 0, stream>>>(x0, wa1, a_sd1);
  gemm_mfma<64, false, true><<<dim3(4, 128), 256, 0, stream>>>(x0, Wg1t, h1, L, 256, 256);
  gat_fused<64, true><<<2048, 256, 0, stream>>>(h1, a_sd1, row_start, csr_src, b1, out1);

  // ---- GAT layer 2 (C=128) ----
  calc_asd<<<128, 256, 0, stream>>>(out1, wa2, a_sd2);
  gemm_mfma<64, false, true><<<dim3(8, 128), 256, 0, stream>>>(out1, Wg2t, h2, L, 512, 256);
  gat_fused<128, true><<<2048, 256, 0, stream>>>(h2, a_sd2, row_start, csr_src, b2, out2);

  // ---- pool + FC head ----
  col_sum_bf16<<<64, 512, 0, stream>>>(out2, pooled);
  fc1<<<32, 256, 0, stream>>>(pooled, fcWt, fcb, hbuf);
  fc2<<<31, 256, 0, stream>>>(hbuf, outWt, outb, outp);
}

// Round 4
// 283.224 us; speedup vs baseline: 2.8401x; 1.0555x over previous
//
#include <hip/hip_runtime.h>
#include <hip/hip_bf16.h>

constexpr int L = 8192;          // nodes
constexpr int H = 4;             // heads (both layers)

typedef __attribute__((ext_vector_type(8))) short bf16x8;
typedef __attribute__((ext_vector_type(8))) unsigned short u16x8;
typedef __attribute__((ext_vector_type(4))) float f32x4;

static __device__ __forceinline__ float lrelu(float e) {
  return e > 0.f ? e : 0.2f * e;
}
static __device__ __forceinline__ float b2f(unsigned short s) {
  return __uint_as_float(((unsigned)s) << 16);
}
static __device__ __forceinline__ unsigned short f2b(float f) {
  __hip_bfloat16 h = __float2bfloat16(f);
  return *reinterpret_cast<unsigned short*>(&h);
}

// ================= merged conversion / transpose / wa / degree-count =================
__global__ void conv_all(const float* __restrict__ seq, const float* __restrict__ W1,
                         const float* __restrict__ W2, const float* __restrict__ Wg1,
                         const float* __restrict__ Wg2, const float* __restrict__ fcW,
                         const float* __restrict__ outW, const int* __restrict__ ei,
                         const float* __restrict__ as1, const float* __restrict__ ad1,
                         const float* __restrict__ as2, const float* __restrict__ ad2,
                         int E, int Etot,
                         __hip_bfloat16* __restrict__ xb, __hip_bfloat16* __restrict__ W1t,
                         __hip_bfloat16* __restrict__ W2t, __hip_bfloat16* __restrict__ Wg1t,
                         __hip_bfloat16* __restrict__ Wg2t, float* __restrict__ fcWt,
                         float* __restrict__ outWt, float* __restrict__ wa1,
                         float* __restrict__ wa2, int* __restrict__ deg) {
  int i = blockIdx.x * 256 + threadIdx.x;
  if (i < 262144) { int r = i >> 5, k = i & 31;
    xb[i] = __float2bfloat16(k < 26 ? seq[r * 26 + k] : 0.f); return; }
  i -= 262144;
  if (i < 32768) { int n = i >> 5, k = i & 31;
    W1t[i] = __float2bfloat16(k < 26 ? W1[k * 1024 + n] : 0.f); return; }
  i -= 32768;
  if (i < 262144) { int n = i >> 10, k = i & 1023;
    W2t[i] = __float2bfloat16(W2[k * 256 + n]); return; }
  i -= 262144;
  if (i < 65536) { int n = i >> 8, k = i & 255;
    Wg1t[i] = __float2bfloat16(Wg1[k * 256 + n]); return; }
  i -= 65536;
  if (i < 131072) { int n = i >> 8, k = i & 255;
    Wg2t[i] = __float2bfloat16(Wg2[k * 512 + n]); return; }
  i -= 131072;
  if (i < 262144) { int o = i >> 9, k = i & 511;
    fcWt[i] = fcW[k * 512 + o]; return; }
  i -= 262144;
  if (i < 262144) { int o = i >> 9, k = i & 511;
    outWt[i] = (o < 489) ? outW[k * 489 + o] : 0.f; return; }
  i -= 262144;
  if (i < 2048) { int k = i >> 3, o = i & 7, h = o & 3;
    const float* av = (o < 4) ? as1 : ad1;
    float s = 0.f;
    for (int c = 0; c < 64; c++) s += Wg1[k * 256 + h * 64 + c] * av[h * 64 + c];
    wa1[i] = s; return; }
  i -= 2048;
  if (i < 2048) { int k = i >> 3, o = i & 7, h = o & 3;
    const float* av = (o < 4) ? as2 : ad2;
    float s = 0.f;
    for (int c = 0; c < 128; c++) s += Wg2[k * 512 + h * 128 + c] * av[h * 128 + c];
    wa2[i] = s; return; }
  i -= 2048;
  if (i < Etot) {
    int dst = (i < E) ? ei[E + i] : (i - E);
    atomicAdd(&deg[dst], 1);
  }
}

// a_sd[L][8] = x[L,256](bf16) @ wa[256,8](f32)
__global__ __launch_bounds__(256) void calc_asd(
    const __hip_bfloat16* __restrict__ x, const float* __restrict__ wa,
    float* __restrict__ a_sd) {
  __shared__ float swa[256][8];
  __shared__ float red[64][4][8];
  int t = threadIdx.x;
  for (int i = t; i < 2048; i += 256) swa[i >> 3][i & 7] = wa[i];
  __syncthreads();
  int rl = t >> 2, q = t & 3;
  int row = blockIdx.x * 64 + rl;
  float p[8] = {};
  const __hip_bfloat16* xr = &x[(size_t)row * 256 + q * 64];
  for (int kk = 0; kk < 64; kk += 8) {
    u16x8 v = *(const u16x8*)&xr[kk];
#pragma unroll
    for (int e = 0; e < 8; e++) {
      float xv = b2f(v[e]);
      int k = q * 64 + kk + e;
      float4 w0 = *(const float4*)&swa[k][0];
      float4 w1 = *(const float4*)&swa[k][4];
      p[0] = fmaf(xv, w0.x, p[0]); p[1] = fmaf(xv, w0.y, p[1]);
      p[2] = fmaf(xv, w0.z, p[2]); p[3] = fmaf(xv, w0.w, p[3]);
      p[4] = fmaf(xv, w1.x, p[4]); p[5] = fmaf(xv, w1.y, p[5]);
      p[6] = fmaf(xv, w1.z, p[6]); p[7] = fmaf(xv, w1.w, p[7]);
    }
  }
#pragma unroll
  for (int o = 0; o < 8; o++) red[rl][q][o] = p[o];
  __syncthreads();
  if (q == 0) {
#pragma unroll
    for (int o = 0; o < 8; o++)
      a_sd[(size_t)row * 8 + o] =
          red[rl][0][o] + red[rl][1][o] + red[rl][2][o] + red[rl][3][o];
  }
}

// ================= bf16 MFMA GEMM: C = op(A[M,K] @ Bt[N,K]^T) =================
template<int BK, bool RELU, bool OUTBF16>
__global__ __launch_bounds__(256) void gemm_mfma(
    const __hip_bfloat16* __restrict__ A, const __hip_bfloat16* __restrict__ Bt,
    void* __restrict__ Cout, int M, int N, int K) {
  __shared__ __align__(16) short As[64][BK + 8];
  __shared__ __align__(16) short Bs[64][BK + 8];
  int tid = threadIdx.x;
  int m0 = blockIdx.y * 64, n0 = blockIdx.x * 64;
  int w = tid >> 6, lane = tid & 63;
  f32x4 acc[4] = {};
  int lrow = tid >> 2;
  int lk = (tid & 3) * 8;
  for (int k0 = 0; k0 < K; k0 += BK) {
#pragma unroll
    for (int lc = 0; lc < BK; lc += 32) {
      *(bf16x8*)&As[lrow][lk + lc] = *(const bf16x8*)&A[(size_t)(m0 + lrow) * K + k0 + lk + lc];
      *(bf16x8*)&Bs[lrow][lk + lc] = *(const bf16x8*)&Bt[(size_t)(n0 + lrow) * K + k0 + lk + lc];
    }
    __syncthreads();
    int r = w * 16 + (lane & 15);
    int kk = (lane >> 4) * 8;
#pragma unroll
    for (int ks = 0; ks < BK; ks += 32) {
      bf16x8 af = *(const bf16x8*)&As[r][kk + ks];
#pragma unroll
      for (int nf = 0; nf < 4; nf++) {
        bf16x8 bfrag = *(const bf16x8*)&Bs[nf * 16 + (lane & 15)][kk + ks];
        acc[nf] = __builtin_amdgcn_mfma_f32_16x16x32_bf16(af, bfrag, acc[nf], 0, 0, 0);
      }
    }
    __syncthreads();
  }
  int col0 = lane & 15, r0 = w * 16 + (lane >> 4) * 4;
#pragma unroll
  for (int nf = 0; nf < 4; nf++) {
#pragma unroll
    for (int j = 0; j < 4; j++) {
      float v = acc[nf][j];
      if (RELU) v = fmaxf(v, 0.f);
      size_t idx = (size_t)(m0 + r0 + j) * N + (n0 + nf * 16 + col0);
      if (OUTBF16) ((__hip_bfloat16*)Cout)[idx] = __float2bfloat16(v);
      else ((float*)Cout)[idx] = v;
    }
  }
}

// ================= CSR build =================
__global__ __launch_bounds__(1024) void scan_deg(const int* __restrict__ deg,
                                                 int* __restrict__ row_start,
                                                 float* __restrict__ pooled) {
  __shared__ int part[1024];
  int tid = threadIdx.x;
  if (tid < 512) pooled[tid] = 0.f;
  int local[8];
  int sum = 0;
#pragma unroll
  for (int j = 0; j < 8; j++) { local[j] = deg[tid * 8 + j]; sum += local[j]; }
  part[tid] = sum;
  __syncthreads();
  for (int off = 1; off < 1024; off <<= 1) {
    int v = part[tid];
    int add = (tid >= off) ? part[tid - off] : 0;
    __syncthreads();
    part[tid] = v + add;
    __syncthreads();
  }
  int base = part[tid] - sum;
#pragma unroll
  for (int j = 0; j < 8; j++) { row_start[tid * 8 + j] = base; base += local[j]; }
  if (tid == 1023) row_start[L] = part[1023];
}

__global__ void scatter_edges(const int* __restrict__ ei, int E, int Etot,
                              const int* __restrict__ row_start,
                              int* __restrict__ cursor, int* __restrict__ csr_src) {
  int e = blockIdx.x * blockDim.x + threadIdx.x;
  if (e >= Etot) return;
  int srcv, dstv;
  if (e < E) { srcv = ei[e]; dstv = ei[E + e]; } else { srcv = dstv = e - E; }
  int pos = row_start[dstv] + atomicAdd(&cursor[dstv], 1);
  csr_src[pos] = srcv;
}

// ================= fused single-sweep softmax+aggregate: one wave per node ======
// Unnormalized accumulate: acc = sum_j exp(e_j) * h[src_j]; denom accumulated
// alongside; divide at the end. No max-subtraction (|e| is small for this data;
// f32 exp has huge headroom).
template<int C, bool OUTBF16>
__global__ __launch_bounds__(256) void gat_fused(
    const __hip_bfloat16* __restrict__ hfeat, const float* __restrict__ a_sd,
    const int* __restrict__ row_start, const int* __restrict__ csr_src,
    const float* __restrict__ bias, void* __restrict__ out) {
  constexpr int HC = 4 * C;
  constexpr int VPT = HC / 64;   // 4 (C=64) or 8 (C=128)
  int wid = threadIdx.x >> 6, lane = threadIdx.x & 63;
  int n = blockIdx.x * 4 + wid;
  int c0 = lane * VPT;
  int hh = c0 / C;
  int rs = row_start[n], re = row_start[n + 1];
  float4 ad4 = *(const float4*)&a_sd[(size_t)n * 8 + 4];

  __shared__ float s_w[4][64][4];   // per-wave alpha staging (4KB)

  float dp[4] = {0.f, 0.f, 0.f, 0.f};
  float acc[VPT] = {};

  for (int base = rs; base < re; base += 64) {
    int cnt = min(64, re - base);
    int srcv = 0;
    float w0 = 0.f, w1 = 0.f, w2 = 0.f, w3 = 0.f;
    if (lane < cnt) {
      srcv = csr_src[base + lane];
      float4 as4 = *(const float4*)&a_sd[(size_t)srcv * 8];
      w0 = __expf(lrelu(as4.x + ad4.x));
      w1 = __expf(lrelu(as4.y + ad4.y));
      w2 = __expf(lrelu(as4.z + ad4.z));
      w3 = __expf(lrelu(as4.w + ad4.w));
    }
    dp[0] += w0; dp[1] += w1; dp[2] += w2; dp[3] += w3;
    float4 wv = {w0, w1, w2, w3};
    *(float4*)&s_w[wid][lane][0] = wv;
    // within-wave LDS write->read ordering (no cross-wave dependency; waves in
    // this block iterate different chunk counts, so __syncthreads is illegal)
    asm volatile("s_waitcnt lgkmcnt(0)" ::: "memory");
#pragma unroll 8
    for (int j = 0; j < cnt; j++) {
      int sr = __builtin_amdgcn_readlane(srcv, j);   // SGPR -> saddr gather
      float av = s_w[wid][j][hh];
      const unsigned short* hp = (const unsigned short*)&hfeat[(size_t)sr * HC + c0];
      if constexpr (VPT == 8) {
        u16x8 v = *(const u16x8*)hp;
#pragma unroll
        for (int k = 0; k < 8; k++) acc[k] = fmaf(av, b2f(v[k]), acc[k]);
      } else {
        ushort4 v = *(const ushort4*)hp;
        acc[0] = fmaf(av, b2f(v.x), acc[0]);
        acc[1] = fmaf(av, b2f(v.y), acc[1]);
        acc[2] = fmaf(av, b2f(v.z), acc[2]);
        acc[3] = fmaf(av, b2f(v.w), acc[3]);
      }
    }
  }

  // ---- denominator: butterfly-sum the 4 heads, select own head ----
#pragma unroll
  for (int off = 32; off > 0; off >>= 1) {
#pragma unroll
    for (int h = 0; h < 4; h++) dp[h] += __shfl_xor(dp[h], off);
  }
  float dsel = hh == 0 ? dp[0] : hh == 1 ? dp[1] : hh == 2 ? dp[2] : dp[3];
  float inv = 1.f / (dsel + 1e-16f);

  // ---- epilogue ----
#pragma unroll
  for (int k = 0; k < VPT; k++)
    acc[k] = fmaxf(fmaf(acc[k], inv, bias[c0 + k]), 0.f);
  if constexpr (OUTBF16) {
    if constexpr (VPT == 8) {
      u16x8 ov;
#pragma unroll
      for (int k = 0; k < 8; k++) ov[k] = f2b(acc[k]);
      *(u16x8*)((unsigned short*)out + (size_t)n * HC + c0) = ov;
    } else {
      ushort4 ov = {f2b(acc[0]), f2b(acc[1]), f2b(acc[2]), f2b(acc[3])};
      *(ushort4*)((unsigned short*)out + (size_t)n * HC + c0) = ov;
    }
  } else {
#pragma unroll
    for (int k = 0; k < VPT; k++) ((float*)out)[(size_t)n * HC + c0 + k] = acc[k];
  }
}

// ================= pooled column sum (bf16 in, f32 atomic out) =================
__global__ __launch_bounds__(512) void col_sum_bf16(const __hip_bfloat16* __restrict__ x,
                                                    float* __restrict__ pooled) {
  int t = threadIdx.x;
  float acc = 0.f;
  for (int r = blockIdx.x; r < L; r += 64)
    acc += b2f(*(const unsigned short*)&x[(size_t)r * 512 + t]);
  atomicAdd(&pooled[t], acc);
}

// ================= FC head (pre-transposed f32 weights) =================
__global__ __launch_bounds__(256) void fc1(const float* __restrict__ pooled,
                                           const float* __restrict__ Wt,
                                           const float* __restrict__ b,
                                           float* __restrict__ out) {
  __shared__ float pv[512];
  __shared__ float red[256];
  int t = threadIdx.x;
  pv[t] = pooled[t]; pv[t + 256] = pooled[t + 256];
  __syncthreads();
  int ol = t >> 4;
  int o = blockIdx.x * 16 + ol;
  int ks = (t & 15) * 32;
  float p = 0.f;
  const float* wr = &Wt[(size_t)o * 512 + ks];
#pragma unroll
  for (int kk = 0; kk < 32; kk++) p = fmaf(pv[ks + kk], wr[kk], p);
  red[t] = p;
  __syncthreads();
  if ((t & 15) == 0) {
    float s2 = 0.f;
#pragma unroll
    for (int i = 0; i < 16; i++) s2 += red[ol * 16 + i];
    out[o] = fmaxf(s2 + b[o], 0.f);
  }
}

__global__ __launch_bounds__(256) void fc2(const float* __restrict__ h,
                                           const float* __restrict__ Wt,
                                           const float* __restrict__ outb,
                                           float* __restrict__ out) {
  __shared__ float pv[512];
  __shared__ float red[256];
  int t = threadIdx.x;
  pv[t] = h[t]; pv[t + 256] = h[t + 256];
  __syncthreads();
  int ol = t >> 4;
  int o = blockIdx.x * 16 + ol;
  int ks = (t & 15) * 32;
  float p = 0.f;
  const float* wr = &Wt[(size_t)o * 512 + ks];
#pragma unroll
  for (int kk = 0; kk < 32; kk++) p = fmaf(pv[ks + kk], wr[kk], p);
  red[t] = p;
  __syncthreads();
  if ((t & 15) == 0 && o < 489) {
    float s2 = 0.f;
#pragma unroll
    for (int i = 0; i < 16; i++) s2 += red[ol * 16 + i];
    out[o] = s2 + outb[o];
  }
}

extern "C" void kernel_launch(void* const* d_in, const int* in_sizes, int n_in,
                              void* d_out, int out_size, void* d_ws, size_t ws_size,
                              hipStream_t stream) {
  const float* seq   = (const float*)d_in[0];
  const int*   ei    = (const int*)d_in[1];
  const float* W1    = (const float*)d_in[2];
  const float* W2    = (const float*)d_in[3];
  const float* Wg1   = (const float*)d_in[4];
  const float* asrc1 = (const float*)d_in[5];
  const float* adst1 = (const float*)d_in[6];
  const float* b1    = (const float*)d_in[7];
  const float* Wg2   = (const float*)d_in[8];
  const float* asrc2 = (const float*)d_in[9];
  const float* adst2 = (const float*)d_in[10];
  const float* b2    = (const float*)d_in[11];
  const float* fcW   = (const float*)d_in[12];
  const float* fcb   = (const float*)d_in[13];
  const float* outW  = (const float*)d_in[14];
  const float* outb  = (const float*)d_in[15];
  float* outp = (float*)d_out;

  const int E = in_sizes[1] / 2;      // 524288
  const int Etot = E + L;             // + self loops

  // ---- workspace layout ----
  char* ws = (char*)d_ws;
  __hip_bfloat16* mlp1 = (__hip_bfloat16*)(ws + 0);           // [L,1024] 16MB
  __hip_bfloat16* out2 = (__hip_bfloat16*)(ws + 0);           // [L,512] 8MB (mlp1 dead)
  __hip_bfloat16* h2   = (__hip_bfloat16*)(ws + (16u << 20)); // [L,512] 8MB
  __hip_bfloat16* x0   = (__hip_bfloat16*)(ws + (24u << 20)); // [L,256] 4MB
  __hip_bfloat16* h1   = (__hip_bfloat16*)(ws + (28u << 20)); // [L,256] 4MB
  __hip_bfloat16* out1 = (__hip_bfloat16*)(ws + (32u << 20)); // [L,256] 4MB
  size_t off = (36u << 20);
  __hip_bfloat16* xb   = (__hip_bfloat16*)(ws + off); off += (size_t)L * 32 * 2;
  __hip_bfloat16* W1t  = (__hip_bfloat16*)(ws + off); off += (size_t)1024 * 32 * 2;
  __hip_bfloat16* W2t  = (__hip_bfloat16*)(ws + off); off += (size_t)256 * 1024 * 2;
  __hip_bfloat16* Wg1t = (__hip_bfloat16*)(ws + off); off += (size_t)256 * 256 * 2;
  __hip_bfloat16* Wg2t = (__hip_bfloat16*)(ws + off); off += (size_t)512 * 256 * 2;
  float* fcWt  = (float*)(ws + off); off += (size_t)512 * 512 * 4;
  float* outWt = (float*)(ws + off); off += (size_t)512 * 512 * 4;
  int* csr_src = (int*)(ws + off); off += (size_t)Etot * 4;
  off = (off + 255) & ~(size_t)255;
  int* row_start = (int*)(ws + off); off += (size_t)(L + 1) * 4;
  off = (off + 255) & ~(size_t)255;
  int* deg    = (int*)(ws + off); off += (size_t)L * 4;
  int* cursor = (int*)(ws + off); off += (size_t)L * 4;   // adjacent to deg
  float* a_sd1 = (float*)(ws + off); off += (size_t)L * 8 * 4;
  float* a_sd2 = (float*)(ws + off); off += (size_t)L * 8 * 4;
  float* wa1 = (float*)(ws + off); off += 2048 * 4;
  float* wa2 = (float*)(ws + off); off += 2048 * 4;
  float* pooled = (float*)(ws + off); off += 512 * 4;
  float* hbuf   = (float*)(ws + off); off += 512 * 4;

  // ---- zero deg+cursor (adjacent) ----
  hipMemsetAsync(deg, 0, (size_t)L * 8, stream);

  // ---- merged conversions + wa + degree count ----
  int convN = 1277952 + 4096 + Etot;
  conv_all<<<(convN + 255) / 256, 256, 0, stream>>>(
      seq, W1, W2, Wg1, Wg2, fcW, outW, ei, asrc1, adst1, asrc2, adst2, E, Etot,
      xb, W1t, W2t, Wg1t, Wg2t, fcWt, outWt, wa1, wa2, deg);

  // ---- CSR ----
  scan_deg<<<1, 1024, 0, stream>>>(deg, row_start, pooled);
  scatter_edges<<<(Etot + 255) / 256, 256, 0, stream>>>(ei, E, Etot, row_start, cursor, csr_src);

  // ---- input MLP ----
  gemm_mfma<32, true, true><<<dim3(16, 128), 256, 0, stream>>>(xb, W1t, mlp1, L, 1024, 32);
  gemm_mfma<64, false, true><<<dim3(4, 128), 256, 0, stream>>>(mlp1, W2t, x0, L, 256, 1024);

  // ---- GAT layer 1 (C=64) ----
  calc_asd<<<128, 256, 0, stream>>>(x0, wa1, a_sd1);
  gemm_mfma<64, false, true><<<dim3(4, 128), 256, 0, stream>>>(x0, Wg1t, h1, L, 256, 256);
  gat_fused<64, true><<<2048, 256, 0, stream>>>(h1, a_sd1, row_start, csr_src, b1, out1);

  // ---- GAT layer 2 (C=128) ----
  calc_asd<<<128, 256, 0, stream>>>(out1, wa2, a_sd2);
  gemm_mfma<64, false, true><<<dim3(8, 128), 256, 0, stream>>>(out1, Wg2t, h2, L, 512, 256);
  gat_fused<128, true><<<2048, 256, 0, stream>>>(h2, a_sd2, row_start, csr_src, b2, out2);

  // ---- pool + FC head ----
  col_sum_bf16<<<64, 512, 0, stream>>>(out2, pooled);
  fc1<<<32, 256, 0, stream>>>(pooled, fcWt, fcb, hbuf);
  fc2<<<31, 256, 0, stream>>>(hbuf, outWt, outb, outp);
}

// Round 5
// 244.278 us; speedup vs baseline: 3.2929x; 1.1594x over previous
//
#include <hip/hip_runtime.h>
#include <hip/hip_bf16.h>

constexpr int L = 8192;          // nodes
constexpr int H = 4;             // heads (both layers)

typedef __attribute__((ext_vector_type(8))) short bf16x8;
typedef __attribute__((ext_vector_type(8))) unsigned short u16x8;
typedef __attribute__((ext_vector_type(4))) float f32x4;

static __device__ __forceinline__ float lrelu(float e) {
  return e > 0.f ? e : 0.2f * e;
}
static __device__ __forceinline__ float b2f(unsigned short s) {
  return __uint_as_float(((unsigned)s) << 16);
}
static __device__ __forceinline__ unsigned short f2b(float f) {
  __hip_bfloat16 h = __float2bfloat16(f);
  return *reinterpret_cast<unsigned short*>(&h);
}

// ================= conversions that are already coalesced + wa + degree/rank ====
__global__ void conv_all(const float* __restrict__ seq, const float* __restrict__ Wg1,
                         const float* __restrict__ Wg2, const int* __restrict__ ei,
                         const float* __restrict__ as1, const float* __restrict__ ad1,
                         const float* __restrict__ as2, const float* __restrict__ ad2,
                         int E, int Etot,
                         __hip_bfloat16* __restrict__ xb, float* __restrict__ wa1,
                         float* __restrict__ wa2, int* __restrict__ deg,
                         int* __restrict__ rank) {
  int i = blockIdx.x * 256 + threadIdx.x;
  if (i < 262144) { int r = i >> 5, k = i & 31;
    xb[i] = __float2bfloat16(k < 26 ? seq[r * 26 + k] : 0.f); return; }
  i -= 262144;
  if (i < 2048) { int k = i >> 3, o = i & 7, h = o & 3;
    const float* av = (o < 4) ? as1 : ad1;
    float s = 0.f;
    for (int c = 0; c < 64; c++) s += Wg1[k * 256 + h * 64 + c] * av[h * 64 + c];
    wa1[i] = s; return; }
  i -= 2048;
  if (i < 2048) { int k = i >> 3, o = i & 7, h = o & 3;
    const float* av = (o < 4) ? as2 : ad2;
    float s = 0.f;
    for (int c = 0; c < 128; c++) s += Wg2[k * 512 + h * 128 + c] * av[h * 128 + c];
    wa2[i] = s; return; }
  i -= 2048;
  if (i < Etot) {
    int dst = (i < E) ? ei[E + i] : (i - E);
    rank[i] = atomicAdd(&deg[dst], 1);
  }
}

// ================= coalesced LDS-tiled transposes (f32 src) =================
// segments (32x32 tiles): W2[1024,256]->bf16[256,1024] (256 tiles),
// Wg1[256,256]->bf16 (64), Wg2[256,512]->bf16[512,256] (128),
// fcW[512,512]->f32 (256), outW[512,489]->f32[512,512] (256),
// W1[26,1024]->bf16[1024,32] pad (32).  total 992 blocks.
__global__ __launch_bounds__(256) void transpose_all(
    const float* __restrict__ W2, const float* __restrict__ Wg1,
    const float* __restrict__ Wg2, const float* __restrict__ fcW,
    const float* __restrict__ outW, const float* __restrict__ W1,
    __hip_bfloat16* __restrict__ W2t, __hip_bfloat16* __restrict__ Wg1t,
    __hip_bfloat16* __restrict__ Wg2t, float* __restrict__ fcWt,
    float* __restrict__ outWt, __hip_bfloat16* __restrict__ W1t) {
  __shared__ float tile[32][33];
  int b = blockIdx.x;
  const float* src; void* dst; bool obf16; int K, N, Kout, kt, nt;
  if (b < 256)            { src = W2;  dst = W2t;  obf16 = true;  K = 1024; N = 256; Kout = 1024; nt = b & 7;  kt = b >> 3; }
  else if ((b -= 256) < 64)  { src = Wg1; dst = Wg1t; obf16 = true;  K = 256;  N = 256; Kout = 256;  nt = b & 7;  kt = b >> 3; }
  else if ((b -= 64) < 128)  { src = Wg2; dst = Wg2t; obf16 = true;  K = 256;  N = 512; Kout = 256;  nt = b & 15; kt = b >> 4; }
  else if ((b -= 128) < 256) { src = fcW; dst = fcWt; obf16 = false; K = 512;  N = 512; Kout = 512;  nt = b & 15; kt = b >> 4; }
  else if ((b -= 256) < 256) { src = outW;dst = outWt;obf16 = false; K = 512;  N = 489; Kout = 512;  nt = b & 15; kt = b >> 4; }
  else { b -= 256;             src = W1;  dst = W1t;  obf16 = true;  K = 26;   N = 1024;Kout = 32;   nt = b;      kt = 0; }
  int t = threadIdx.x;
  int lr = t >> 3, lc4 = (t & 7) * 4;
  int gk = kt * 32 + lr, gn = nt * 32 + lc4;
  float4 v = {0.f, 0.f, 0.f, 0.f};
  if (gk < K) {
    const float* p = &src[(size_t)gk * N + gn];
    v.x = (gn + 0 < N) ? p[0] : 0.f;
    v.y = (gn + 1 < N) ? p[1] : 0.f;
    v.z = (gn + 2 < N) ? p[2] : 0.f;
    v.w = (gn + 3 < N) ? p[3] : 0.f;
  }
  tile[lr][lc4 + 0] = v.x; tile[lr][lc4 + 1] = v.y;
  tile[lr][lc4 + 2] = v.z; tile[lr][lc4 + 3] = v.w;
  __syncthreads();
  int on = nt * 32 + lr, ok = kt * 32 + lc4;
  if (on >= N || ok >= Kout) return;
  float o0 = tile[lc4 + 0][lr], o1 = tile[lc4 + 1][lr];
  float o2 = tile[lc4 + 2][lr], o3 = tile[lc4 + 3][lr];
  if (obf16) {
    ushort4 u = {f2b(o0), f2b(o1), f2b(o2), f2b(o3)};
    *(ushort4*)&((__hip_bfloat16*)dst)[(size_t)on * Kout + ok] = u;
  } else {
    float4 u = {o0, o1, o2, o3};
    *(float4*)&((float*)dst)[(size_t)on * Kout + ok] = u;
  }
}

// a_sd[L][8] = x[L,256](bf16) @ wa[256,8](f32)
__global__ __launch_bounds__(256) void calc_asd(
    const __hip_bfloat16* __restrict__ x, const float* __restrict__ wa,
    float* __restrict__ a_sd) {
  __shared__ float swa[256][8];
  __shared__ float red[64][4][8];
  int t = threadIdx.x;
  for (int i = t; i < 2048; i += 256) swa[i >> 3][i & 7] = wa[i];
  __syncthreads();
  int rl = t >> 2, q = t & 3;
  int row = blockIdx.x * 64 + rl;
  float p[8] = {};
  const __hip_bfloat16* xr = &x[(size_t)row * 256 + q * 64];
  for (int kk = 0; kk < 64; kk += 8) {
    u16x8 v = *(const u16x8*)&xr[kk];
#pragma unroll
    for (int e = 0; e < 8; e++) {
      float xv = b2f(v[e]);
      int k = q * 64 + kk + e;
      float4 w0 = *(const float4*)&swa[k][0];
      float4 w1 = *(const float4*)&swa[k][4];
      p[0] = fmaf(xv, w0.x, p[0]); p[1] = fmaf(xv, w0.y, p[1]);
      p[2] = fmaf(xv, w0.z, p[2]); p[3] = fmaf(xv, w0.w, p[3]);
      p[4] = fmaf(xv, w1.x, p[4]); p[5] = fmaf(xv, w1.y, p[5]);
      p[6] = fmaf(xv, w1.z, p[6]); p[7] = fmaf(xv, w1.w, p[7]);
    }
  }
#pragma unroll
  for (int o = 0; o < 8; o++) red[rl][q][o] = p[o];
  __syncthreads();
  if (q == 0) {
#pragma unroll
    for (int o = 0; o < 8; o++)
      a_sd[(size_t)row * 8 + o] =
          red[rl][0][o] + red[rl][1][o] + red[rl][2][o] + red[rl][3][o];
  }
}

// ================= bf16 MFMA GEMM: C = op(A[M,K] @ Bt[N,K]^T) =================
template<int BK, bool RELU, bool OUTBF16>
__global__ __launch_bounds__(256) void gemm_mfma(
    const __hip_bfloat16* __restrict__ A, const __hip_bfloat16* __restrict__ Bt,
    void* __restrict__ Cout, int M, int N, int K) {
  __shared__ __align__(16) short As[64][BK + 8];
  __shared__ __align__(16) short Bs[64][BK + 8];
  int tid = threadIdx.x;
  int m0 = blockIdx.y * 64, n0 = blockIdx.x * 64;
  int w = tid >> 6, lane = tid & 63;
  f32x4 acc[4] = {};
  int lrow = tid >> 2;
  int lk = (tid & 3) * 8;
  for (int k0 = 0; k0 < K; k0 += BK) {
#pragma unroll
    for (int lc = 0; lc < BK; lc += 32) {
      *(bf16x8*)&As[lrow][lk + lc] = *(const bf16x8*)&A[(size_t)(m0 + lrow) * K + k0 + lk + lc];
      *(bf16x8*)&Bs[lrow][lk + lc] = *(const bf16x8*)&Bt[(size_t)(n0 + lrow) * K + k0 + lk + lc];
    }
    __syncthreads();
    int r = w * 16 + (lane & 15);
    int kk = (lane >> 4) * 8;
#pragma unroll
    for (int ks = 0; ks < BK; ks += 32) {
      bf16x8 af = *(const bf16x8*)&As[r][kk + ks];
#pragma unroll
      for (int nf = 0; nf < 4; nf++) {
        bf16x8 bfrag = *(const bf16x8*)&Bs[nf * 16 + (lane & 15)][kk + ks];
        acc[nf] = __builtin_amdgcn_mfma_f32_16x16x32_bf16(af, bfrag, acc[nf], 0, 0, 0);
      }
    }
    __syncthreads();
  }
  int col0 = lane & 15, r0 = w * 16 + (lane >> 4) * 4;
#pragma unroll
  for (int nf = 0; nf < 4; nf++) {
#pragma unroll
    for (int j = 0; j < 4; j++) {
      float v = acc[nf][j];
      if (RELU) v = fmaxf(v, 0.f);
      size_t idx = (size_t)(m0 + r0 + j) * N + (n0 + nf * 16 + col0);
      if (OUTBF16) ((__hip_bfloat16*)Cout)[idx] = __float2bfloat16(v);
      else ((float*)Cout)[idx] = v;
    }
  }
}

// ================= CSR build =================
__global__ __launch_bounds__(1024) void scan_deg(const int* __restrict__ deg,
                                                 int* __restrict__ row_start,
                                                 float* __restrict__ pooled) {
  __shared__ int part[1024];
  int tid = threadIdx.x;
  if (tid < 512) pooled[tid] = 0.f;
  int local[8];
  int sum = 0;
#pragma unroll
  for (int j = 0; j < 8; j++) { local[j] = deg[tid * 8 + j]; sum += local[j]; }
  part[tid] = sum;
  __syncthreads();
  for (int off = 1; off < 1024; off <<= 1) {
    int v = part[tid];
    int add = (tid >= off) ? part[tid - off] : 0;
    __syncthreads();
    part[tid] = v + add;
    __syncthreads();
  }
  int base = part[tid] - sum;
#pragma unroll
  for (int j = 0; j < 8; j++) { row_start[tid * 8 + j] = base; base += local[j]; }
  if (tid == 1023) row_start[L] = part[1023];
}

// atomic-free scatter using precomputed ranks
__global__ void scatter_edges(const int* __restrict__ ei, int E, int Etot,
                              const int* __restrict__ row_start,
                              const int* __restrict__ rank, int* __restrict__ csr_src) {
  int e = blockIdx.x * blockDim.x + threadIdx.x;
  if (e >= Etot) return;
  int srcv, dstv;
  if (e < E) { srcv = ei[e]; dstv = ei[E + e]; } else { srcv = dstv = e - E; }
  csr_src[row_start[dstv] + rank[e]] = srcv;
}

// ================= fused single-sweep softmax+aggregate: one wave per node ======
// acc = sum_j exp(e_j)*h[src_j] (unnormalized) alongside denom; divide at end.
// Inner gather software-pipelined BATCH-deep for memory-level parallelism.
template<int C, bool OUTBF16>
__global__ __launch_bounds__(256) void gat_fused(
    const __hip_bfloat16* __restrict__ hfeat, const float* __restrict__ a_sd,
    const int* __restrict__ row_start, const int* __restrict__ csr_src,
    const float* __restrict__ bias, void* __restrict__ out) {
  constexpr int HC = 4 * C;
  constexpr int VPT = HC / 64;                 // 4 (C=64) or 8 (C=128)
  constexpr int BATCH = (VPT == 8) ? 12 : 16;  // in-flight row gathers
  int wid = threadIdx.x >> 6, lane = threadIdx.x & 63;
  int n = blockIdx.x * 4 + wid;
  int c0 = lane * VPT;
  int hh = c0 / C;
  int rs = row_start[n], re = row_start[n + 1];
  float4 ad4 = *(const float4*)&a_sd[(size_t)n * 8 + 4];
  float bv[VPT];
#pragma unroll
  for (int k = 0; k < VPT; k++) bv[k] = bias[c0 + k];

  __shared__ float s_w[4][64][4];   // per-wave alpha staging (4KB)
  float dp[4] = {0.f, 0.f, 0.f, 0.f};
  float acc[VPT] = {};
  const unsigned short* hbase = (const unsigned short*)hfeat;

  for (int base = rs; base < re; base += 64) {
    int cnt = min(64, re - base);
    int srcv = 0;
    float w0 = 0.f, w1 = 0.f, w2 = 0.f, w3 = 0.f;
    if (lane < cnt) {
      srcv = csr_src[base + lane];
      float4 as4 = *(const float4*)&a_sd[(size_t)srcv * 8];
      w0 = __expf(lrelu(as4.x + ad4.x));
      w1 = __expf(lrelu(as4.y + ad4.y));
      w2 = __expf(lrelu(as4.z + ad4.z));
      w3 = __expf(lrelu(as4.w + ad4.w));
    }
    dp[0] += w0; dp[1] += w1; dp[2] += w2; dp[3] += w3;
    float4 wv = {w0, w1, w2, w3};
    *(float4*)&s_w[wid][lane][0] = wv;
    // within-wave LDS write->read ordering (cross-wave sync illegal here)
    asm volatile("s_waitcnt lgkmcnt(0)" ::: "memory");
    int j = 0;
    for (; j + BATCH <= cnt; j += BATCH) {
      int srs[BATCH];
#pragma unroll
      for (int k = 0; k < BATCH; k++) srs[k] = __builtin_amdgcn_readlane(srcv, j + k);
      if constexpr (VPT == 8) {
        u16x8 v[BATCH];
#pragma unroll
        for (int k = 0; k < BATCH; k++)
          v[k] = *(const u16x8*)&hbase[(size_t)srs[k] * HC + c0];
#pragma unroll
        for (int k = 0; k < BATCH; k++) {
          float av = s_w[wid][j + k][hh];
#pragma unroll
          for (int q = 0; q < 8; q++) acc[q] = fmaf(av, b2f(v[k][q]), acc[q]);
        }
      } else {
        ushort4 v[BATCH];
#pragma unroll
        for (int k = 0; k < BATCH; k++)
          v[k] = *(const ushort4*)&hbase[(size_t)srs[k] * HC + c0];
#pragma unroll
        for (int k = 0; k < BATCH; k++) {
          float av = s_w[wid][j + k][hh];
          acc[0] = fmaf(av, b2f(v[k].x), acc[0]);
          acc[1] = fmaf(av, b2f(v[k].y), acc[1]);
          acc[2] = fmaf(av, b2f(v[k].z), acc[2]);
          acc[3] = fmaf(av, b2f(v[k].w), acc[3]);
        }
      }
    }
    for (; j < cnt; j++) {
      int sr = __builtin_amdgcn_readlane(srcv, j);
      float av = s_w[wid][j][hh];
      const unsigned short* hp = &hbase[(size_t)sr * HC + c0];
      if constexpr (VPT == 8) {
        u16x8 v = *(const u16x8*)hp;
#pragma unroll
        for (int q = 0; q < 8; q++) acc[q] = fmaf(av, b2f(v[q]), acc[q]);
      } else {
        ushort4 v = *(const ushort4*)hp;
        acc[0] = fmaf(av, b2f(v.x), acc[0]);
        acc[1] = fmaf(av, b2f(v.y), acc[1]);
        acc[2] = fmaf(av, b2f(v.z), acc[2]);
        acc[3] = fmaf(av, b2f(v.w), acc[3]);
      }
    }
  }

  // ---- denominator: butterfly-sum the 4 heads, select own head ----
#pragma unroll
  for (int off = 32; off > 0; off >>= 1) {
#pragma unroll
    for (int h = 0; h < 4; h++) dp[h] += __shfl_xor(dp[h], off);
  }
  float dsel = hh == 0 ? dp[0] : hh == 1 ? dp[1] : hh == 2 ? dp[2] : dp[3];
  float inv = 1.f / (dsel + 1e-16f);

  // ---- epilogue ----
#pragma unroll
  for (int k = 0; k < VPT; k++)
    acc[k] = fmaxf(fmaf(acc[k], inv, bv[k]), 0.f);
  if constexpr (OUTBF16) {
    if constexpr (VPT == 8) {
      u16x8 ov;
#pragma unroll
      for (int k = 0; k < 8; k++) ov[k] = f2b(acc[k]);
      *(u16x8*)((unsigned short*)out + (size_t)n * HC + c0) = ov;
    } else {
      ushort4 ov = {f2b(acc[0]), f2b(acc[1]), f2b(acc[2]), f2b(acc[3])};
      *(ushort4*)((unsigned short*)out + (size_t)n * HC + c0) = ov;
    }
  } else {
#pragma unroll
    for (int k = 0; k < VPT; k++) ((float*)out)[(size_t)n * HC + c0 + k] = acc[k];
  }
}

// ================= pooled column sum (bf16 in, f32 atomic out) =================
__global__ __launch_bounds__(512) void col_sum_bf16(const __hip_bfloat16* __restrict__ x,
                                                    float* __restrict__ pooled) {
  int t = threadIdx.x;
  float acc = 0.f;
  for (int r = blockIdx.x; r < L; r += 64)
    acc += b2f(*(const unsigned short*)&x[(size_t)r * 512 + t]);
  atomicAdd(&pooled[t], acc);
}

// ================= FC head (pre-transposed f32 weights) =================
__global__ __launch_bounds__(256) void fc1(const float* __restrict__ pooled,
                                           const float* __restrict__ Wt,
                                           const float* __restrict__ b,
                                           float* __restrict__ out) {
  __shared__ float pv[512];
  __shared__ float red[256];
  int t = threadIdx.x;
  pv[t] = pooled[t]; pv[t + 256] = pooled[t + 256];
  __syncthreads();
  int ol = t >> 4;
  int o = blockIdx.x * 16 + ol;
  int ks = (t & 15) * 32;
  float p = 0.f;
  const float* wr = &Wt[(size_t)o * 512 + ks];
#pragma unroll
  for (int kk = 0; kk < 32; kk++) p = fmaf(pv[ks + kk], wr[kk], p);
  red[t] = p;
  __syncthreads();
  if ((t & 15) == 0) {
    float s2 = 0.f;
#pragma unroll
    for (int i = 0; i < 16; i++) s2 += red[ol * 16 + i];
    out[o] = fmaxf(s2 + b[o], 0.f);
  }
}

__global__ __launch_bounds__(256) void fc2(const float* __restrict__ h,
                                           const float* __restrict__ Wt,
                                           const float* __restrict__ outb,
                                           float* __restrict__ out) {
  __shared__ float pv[512];
  __shared__ float red[256];
  int t = threadIdx.x;
  pv[t] = h[t]; pv[t + 256] = h[t + 256];
  __syncthreads();
  int ol = t >> 4;
  int o = blockIdx.x * 16 + ol;
  int ks = (t & 15) * 32;
  float p = 0.f;
  const float* wr = &Wt[(size_t)o * 512 + ks];
#pragma unroll
  for (int kk = 0; kk < 32; kk++) p = fmaf(pv[ks + kk], wr[kk], p);
  red[t] = p;
  __syncthreads();
  if ((t & 15) == 0 && o < 489) {
    float s2 = 0.f;
#pragma unroll
    for (int i = 0; i < 16; i++) s2 += red[ol * 16 + i];
    out[o] = s2 + outb[o];
  }
}

extern "C" void kernel_launch(void* const* d_in, const int* in_sizes, int n_in,
                              void* d_out, int out_size, void* d_ws, size_t ws_size,
                              hipStream_t stream) {
  const float* seq   = (const float*)d_in[0];
  const int*   ei    = (const int*)d_in[1];
  const float* W1    = (const float*)d_in[2];
  const float* W2    = (const float*)d_in[3];
  const float* Wg1   = (const float*)d_in[4];
  const float* asrc1 = (const float*)d_in[5];
  const float* adst1 = (const float*)d_in[6];
  const float* b1    = (const float*)d_in[7];
  const float* Wg2   = (const float*)d_in[8];
  const float* asrc2 = (const float*)d_in[9];
  const float* adst2 = (const float*)d_in[10];
  const float* b2    = (const float*)d_in[11];
  const float* fcW   = (const float*)d_in[12];
  const float* fcb   = (const float*)d_in[13];
  const float* outW  = (const float*)d_in[14];
  const float* outb  = (const float*)d_in[15];
  float* outp = (float*)d_out;

  const int E = in_sizes[1] / 2;      // 524288
  const int Etot = E + L;             // + self loops

  // ---- workspace layout ----
  char* ws = (char*)d_ws;
  __hip_bfloat16* mlp1 = (__hip_bfloat16*)(ws + 0);           // [L,1024] 16MB
  __hip_bfloat16* out2 = (__hip_bfloat16*)(ws + 0);           // [L,512] 8MB (mlp1 dead)
  __hip_bfloat16* h2   = (__hip_bfloat16*)(ws + (16u << 20)); // [L,512] 8MB
  __hip_bfloat16* x0   = (__hip_bfloat16*)(ws + (24u << 20)); // [L,256] 4MB
  __hip_bfloat16* h1   = (__hip_bfloat16*)(ws + (28u << 20)); // [L,256] 4MB
  __hip_bfloat16* out1 = (__hip_bfloat16*)(ws + (32u << 20)); // [L,256] 4MB
  size_t off = (36u << 20);
  __hip_bfloat16* xb   = (__hip_bfloat16*)(ws + off); off += (size_t)L * 32 * 2;
  __hip_bfloat16* W1t  = (__hip_bfloat16*)(ws + off); off += (size_t)1024 * 32 * 2;
  __hip_bfloat16* W2t  = (__hip_bfloat16*)(ws + off); off += (size_t)256 * 1024 * 2;
  __hip_bfloat16* Wg1t = (__hip_bfloat16*)(ws + off); off += (size_t)256 * 256 * 2;
  __hip_bfloat16* Wg2t = (__hip_bfloat16*)(ws + off); off += (size_t)512 * 256 * 2;
  float* fcWt  = (float*)(ws + off); off += (size_t)512 * 512 * 4;
  float* outWt = (float*)(ws + off); off += (size_t)512 * 512 * 4;
  int* csr_src = (int*)(ws + off); off += (size_t)Etot * 4;
  int* rank    = (int*)(ws + off); off += (size_t)Etot * 4;
  off = (off + 255) & ~(size_t)255;
  int* row_start = (int*)(ws + off); off += (size_t)(L + 1) * 4;
  off = (off + 255) & ~(size_t)255;
  int* deg    = (int*)(ws + off); off += (size_t)L * 4;
  float* a_sd1 = (float*)(ws + off); off += (size_t)L * 8 * 4;
  float* a_sd2 = (float*)(ws + off); off += (size_t)L * 8 * 4;
  float* wa1 = (float*)(ws + off); off += 2048 * 4;
  float* wa2 = (float*)(ws + off); off += 2048 * 4;
  float* pooled = (float*)(ws + off); off += 512 * 4;
  float* hbuf   = (float*)(ws + off); off += 512 * 4;

  // ---- zero deg ----
  hipMemsetAsync(deg, 0, (size_t)L * 4, stream);

  // ---- conversions / transposes / wa / degree+rank ----
  int convN = 262144 + 4096 + Etot;
  conv_all<<<(convN + 255) / 256, 256, 0, stream>>>(
      seq, Wg1, Wg2, ei, asrc1, adst1, asrc2, adst2, E, Etot,
      xb, wa1, wa2, deg, rank);
  transpose_all<<<992, 256, 0, stream>>>(W2, Wg1, Wg2, fcW, outW, W1,
                                         W2t, Wg1t, Wg2t, fcWt, outWt, W1t);

  // ---- CSR ----
  scan_deg<<<1, 1024, 0, stream>>>(deg, row_start, pooled);
  scatter_edges<<<(Etot + 255) / 256, 256, 0, stream>>>(ei, E, Etot, row_start, rank, csr_src);

  // ---- input MLP ----
  gemm_mfma<32, true, true><<<dim3(16, 128), 256, 0, stream>>>(xb, W1t, mlp1, L, 1024, 32);
  gemm_mfma<64, false, true><<<dim3(4, 128), 256, 0, stream>>>(mlp1, W2t, x0, L, 256, 1024);

  // ---- GAT layer 1 (C=64) ----
  calc_asd<<<128, 256, 0, stream>>>(x0, wa1, a_sd1);
  gemm_mfma<64, false, true><<<dim3(4, 128), 256, 0, stream>>>(x0, Wg1t, h1, L, 256, 256);
  gat_fused<64, true><<<2048, 256, 0, stream>>>(h1, a_sd1, row_start, csr_src, b1, out1);

  // ---- GAT layer 2 (C=128) ----
  calc_asd<<<128, 256, 0, stream>>>(out1, wa2, a_sd2);
  gemm_mfma<64, false, true><<<dim3(8, 128), 256, 0, stream>>>(out1, Wg2t, h2, L, 512, 256);
  gat_fused<128, true><<<2048, 256, 0, stream>>>(h2, a_sd2, row_start, csr_src, b2, out2);

  // ---- pool + FC head ----
  col_sum_bf16<<<64, 512, 0, stream>>>(out2, pooled);
  fc1<<<32, 256, 0, stream>>>(pooled, fcWt, fcb, hbuf);
  fc2<<<31, 256, 0, stream>>>(hbuf, outWt, outb, outp);
}

// Round 6
// 238.542 us; speedup vs baseline: 3.3721x; 1.0240x over previous
//
#include <hip/hip_runtime.h>
#include <hip/hip_bf16.h>

constexpr int L = 8192;          // nodes
constexpr int H = 4;             // heads (both layers)

typedef __attribute__((ext_vector_type(8))) short bf16x8;
typedef __attribute__((ext_vector_type(8))) unsigned short u16x8;
typedef __attribute__((ext_vector_type(4))) float f32x4;

static __device__ __forceinline__ float lrelu(float e) {
  return e > 0.f ? e : 0.2f * e;
}
static __device__ __forceinline__ float b2f(unsigned short s) {
  return __uint_as_float(((unsigned)s) << 16);
}
static __device__ __forceinline__ unsigned short f2b(float f) {
  __hip_bfloat16 h = __float2bfloat16(f);
  return *reinterpret_cast<unsigned short*>(&h);
}

// ========== merged: LDS-tiled transposes (blocks 0..991) + elementwise conv ====
// transpose segments (32x32 tiles): W2(256) Wg1(64) Wg2(128) fcW(256) outW(256) W1(32)
// conv segments: xb 262144, wa1 2048, wa2 2048, rank/deg Etot
__global__ __launch_bounds__(256) void conv_combo(
    const float* __restrict__ seq, const float* __restrict__ W1,
    const float* __restrict__ W2, const float* __restrict__ Wg1,
    const float* __restrict__ Wg2, const float* __restrict__ fcW,
    const float* __restrict__ outW, const int* __restrict__ ei,
    const float* __restrict__ as1, const float* __restrict__ ad1,
    const float* __restrict__ as2, const float* __restrict__ ad2,
    int E, int Etot,
    __hip_bfloat16* __restrict__ xb, __hip_bfloat16* __restrict__ W1t,
    __hip_bfloat16* __restrict__ W2t, __hip_bfloat16* __restrict__ Wg1t,
    __hip_bfloat16* __restrict__ Wg2t, float* __restrict__ fcWt,
    float* __restrict__ outWt, float* __restrict__ wa1, float* __restrict__ wa2,
    int* __restrict__ deg, int* __restrict__ rank) {
  __shared__ float tile[32][33];
  if (blockIdx.x < 992) {
    int b = blockIdx.x;
    const float* src; void* dst; bool obf16; int K, N, Kout, kt, nt;
    if (b < 256)               { src = W2;  dst = W2t;  obf16 = true;  K = 1024; N = 256; Kout = 1024; nt = b & 7;  kt = b >> 3; }
    else if ((b -= 256) < 64)  { src = Wg1; dst = Wg1t; obf16 = true;  K = 256;  N = 256; Kout = 256;  nt = b & 7;  kt = b >> 3; }
    else if ((b -= 64) < 128)  { src = Wg2; dst = Wg2t; obf16 = true;  K = 256;  N = 512; Kout = 256;  nt = b & 15; kt = b >> 4; }
    else if ((b -= 128) < 256) { src = fcW; dst = fcWt; obf16 = false; K = 512;  N = 512; Kout = 512;  nt = b & 15; kt = b >> 4; }
    else if ((b -= 256) < 256) { src = outW;dst = outWt;obf16 = false; K = 512;  N = 489; Kout = 512;  nt = b & 15; kt = b >> 4; }
    else { b -= 256;             src = W1;  dst = W1t;  obf16 = true;  K = 26;   N = 1024;Kout = 32;   nt = b;      kt = 0; }
    int t = threadIdx.x;
    int lr = t >> 3, lc4 = (t & 7) * 4;
    int gk = kt * 32 + lr, gn = nt * 32 + lc4;
    float4 v = {0.f, 0.f, 0.f, 0.f};
    if (gk < K) {
      const float* p = &src[(size_t)gk * N + gn];
      v.x = (gn + 0 < N) ? p[0] : 0.f;
      v.y = (gn + 1 < N) ? p[1] : 0.f;
      v.z = (gn + 2 < N) ? p[2] : 0.f;
      v.w = (gn + 3 < N) ? p[3] : 0.f;
    }
    tile[lr][lc4 + 0] = v.x; tile[lr][lc4 + 1] = v.y;
    tile[lr][lc4 + 2] = v.z; tile[lr][lc4 + 3] = v.w;
    __syncthreads();
    int on = nt * 32 + lr, ok = kt * 32 + lc4;
    if (on >= N || ok >= Kout) return;
    float o0 = tile[lc4 + 0][lr], o1 = tile[lc4 + 1][lr];
    float o2 = tile[lc4 + 2][lr], o3 = tile[lc4 + 3][lr];
    if (obf16) {
      ushort4 u = {f2b(o0), f2b(o1), f2b(o2), f2b(o3)};
      *(ushort4*)&((__hip_bfloat16*)dst)[(size_t)on * Kout + ok] = u;
    } else {
      float4 u = {o0, o1, o2, o3};
      *(float4*)&((float*)dst)[(size_t)on * Kout + ok] = u;
    }
    return;
  }
  int i = (blockIdx.x - 992) * 256 + threadIdx.x;
  if (i < 262144) { int r = i >> 5, k = i & 31;
    xb[i] = __float2bfloat16(k < 26 ? seq[r * 26 + k] : 0.f); return; }
  i -= 262144;
  if (i < 2048) { int k = i >> 3, o = i & 7, h = o & 3;
    const float* av = (o < 4) ? as1 : ad1;
    float s = 0.f;
    for (int c = 0; c < 64; c++) s += Wg1[k * 256 + h * 64 + c] * av[h * 64 + c];
    wa1[i] = s; return; }
  i -= 2048;
  if (i < 2048) { int k = i >> 3, o = i & 7, h = o & 3;
    const float* av = (o < 4) ? as2 : ad2;
    float s = 0.f;
    for (int c = 0; c < 128; c++) s += Wg2[k * 512 + h * 128 + c] * av[h * 128 + c];
    wa2[i] = s; return; }
  i -= 2048;
  if (i < Etot) {
    int dst = (i < E) ? ei[E + i] : (i - E);
    rank[i] = atomicAdd(&deg[dst], 1);
  }
}

// a_sd[L][8] = x[L,256](bf16) @ wa[256,8](f32)
__global__ __launch_bounds__(256) void calc_asd(
    const __hip_bfloat16* __restrict__ x, const float* __restrict__ wa,
    float* __restrict__ a_sd) {
  __shared__ float swa[256][8];
  __shared__ float red[64][4][8];
  int t = threadIdx.x;
  for (int i = t; i < 2048; i += 256) swa[i >> 3][i & 7] = wa[i];
  __syncthreads();
  int rl = t >> 2, q = t & 3;
  int row = blockIdx.x * 64 + rl;
  float p[8] = {};
  const __hip_bfloat16* xr = &x[(size_t)row * 256 + q * 64];
  for (int kk = 0; kk < 64; kk += 8) {
    u16x8 v = *(const u16x8*)&xr[kk];
#pragma unroll
    for (int e = 0; e < 8; e++) {
      float xv = b2f(v[e]);
      int k = q * 64 + kk + e;
      float4 w0 = *(const float4*)&swa[k][0];
      float4 w1 = *(const float4*)&swa[k][4];
      p[0] = fmaf(xv, w0.x, p[0]); p[1] = fmaf(xv, w0.y, p[1]);
      p[2] = fmaf(xv, w0.z, p[2]); p[3] = fmaf(xv, w0.w, p[3]);
      p[4] = fmaf(xv, w1.x, p[4]); p[5] = fmaf(xv, w1.y, p[5]);
      p[6] = fmaf(xv, w1.z, p[6]); p[7] = fmaf(xv, w1.w, p[7]);
    }
  }
#pragma unroll
  for (int o = 0; o < 8; o++) red[rl][q][o] = p[o];
  __syncthreads();
  if (q == 0) {
#pragma unroll
    for (int o = 0; o < 8; o++)
      a_sd[(size_t)row * 8 + o] =
          red[rl][0][o] + red[rl][1][o] + red[rl][2][o] + red[rl][3][o];
  }
}

// ================= bf16 MFMA GEMM: C = op(A[M,K] @ Bt[N,K]^T) =================
template<int BK, bool RELU, bool OUTBF16>
__global__ __launch_bounds__(256) void gemm_mfma(
    const __hip_bfloat16* __restrict__ A, const __hip_bfloat16* __restrict__ Bt,
    void* __restrict__ Cout, int M, int N, int K) {
  __shared__ __align__(16) short As[64][BK + 8];
  __shared__ __align__(16) short Bs[64][BK + 8];
  int tid = threadIdx.x;
  int m0 = blockIdx.y * 64, n0 = blockIdx.x * 64;
  int w = tid >> 6, lane = tid & 63;
  f32x4 acc[4] = {};
  int lrow = tid >> 2;
  int lk = (tid & 3) * 8;
  for (int k0 = 0; k0 < K; k0 += BK) {
#pragma unroll
    for (int lc = 0; lc < BK; lc += 32) {
      *(bf16x8*)&As[lrow][lk + lc] = *(const bf16x8*)&A[(size_t)(m0 + lrow) * K + k0 + lk + lc];
      *(bf16x8*)&Bs[lrow][lk + lc] = *(const bf16x8*)&Bt[(size_t)(n0 + lrow) * K + k0 + lk + lc];
    }
    __syncthreads();
    int r = w * 16 + (lane & 15);
    int kk = (lane >> 4) * 8;
#pragma unroll
    for (int ks = 0; ks < BK; ks += 32) {
      bf16x8 af = *(const bf16x8*)&As[r][kk + ks];
#pragma unroll
      for (int nf = 0; nf < 4; nf++) {
        bf16x8 bfrag = *(const bf16x8*)&Bs[nf * 16 + (lane & 15)][kk + ks];
        acc[nf] = __builtin_amdgcn_mfma_f32_16x16x32_bf16(af, bfrag, acc[nf], 0, 0, 0);
      }
    }
    __syncthreads();
  }
  int col0 = lane & 15, r0 = w * 16 + (lane >> 4) * 4;
#pragma unroll
  for (int nf = 0; nf < 4; nf++) {
#pragma unroll
    for (int j = 0; j < 4; j++) {
      float v = acc[nf][j];
      if (RELU) v = fmaxf(v, 0.f);
      size_t idx = (size_t)(m0 + r0 + j) * N + (n0 + nf * 16 + col0);
      if (OUTBF16) ((__hip_bfloat16*)Cout)[idx] = __float2bfloat16(v);
      else ((float*)Cout)[idx] = v;
    }
  }
}

// ================= CSR build: shuffle-based scan (1 barrier) =================
__global__ __launch_bounds__(1024) void scan_deg(const int* __restrict__ deg,
                                                 int* __restrict__ row_start,
                                                 float* __restrict__ pooled) {
  __shared__ int wsum[16];
  int t = threadIdx.x;
  if (t < 512) pooled[t] = 0.f;
  int lane = t & 63, w = t >> 6;
  int local[8];
  int sum = 0;
#pragma unroll
  for (int j = 0; j < 8; j++) { local[j] = deg[t * 8 + j]; sum += local[j]; }
  int v = sum;
#pragma unroll
  for (int off = 1; off < 64; off <<= 1) {
    int u = __shfl_up(v, off);
    if (lane >= off) v += u;
  }
  if (lane == 63) wsum[w] = v;
  __syncthreads();
  int woff = 0;
  for (int i = 0; i < w; i++) woff += wsum[i];
  int base = woff + v - sum;   // exclusive prefix
#pragma unroll
  for (int j = 0; j < 8; j++) { row_start[t * 8 + j] = base; base += local[j]; }
  if (t == 1023) row_start[L] = base;
}

// atomic-free scatter using precomputed ranks
__global__ void scatter_edges(const int* __restrict__ ei, int E, int Etot,
                              const int* __restrict__ row_start,
                              const int* __restrict__ rank, int* __restrict__ csr_src) {
  int e = blockIdx.x * blockDim.x + threadIdx.x;
  if (e >= Etot) return;
  int srcv, dstv;
  if (e < E) { srcv = ei[e]; dstv = ei[E + e]; } else { srcv = dstv = e - E; }
  csr_src[row_start[dstv] + rank[e]] = srcv;
}

// ====== fused single-sweep softmax+aggregate, chunk-pipelined; 1 wave/node =====
// acc = sum_j exp(e_j)*h[src_j] (unnormalized) + denom; divide at end.
// Next chunk's csr_src prefetched before the gather; its a_sd gather issued one
// batch into the gather loop (csr data has landed by then).
// ASD2: layer-1 instance also emits a_sd2[n][8] = relu_out1[n] @ wa2.
template<int C, bool ASD2, bool OUTBF16>
__global__ __launch_bounds__(128) void gat_fused(
    const __hip_bfloat16* __restrict__ hfeat, const float* __restrict__ a_sd,
    const int* __restrict__ row_start, const int* __restrict__ csr_src,
    const float* __restrict__ bias, void* __restrict__ out,
    const float* __restrict__ wa2, float* __restrict__ a_sd2) {
  constexpr int HC = 4 * C;
  constexpr int VPT = HC / 64;                 // 4 (C=64) or 8 (C=128)
  constexpr int BATCH = (VPT == 8) ? 12 : 16;  // in-flight row gathers
  int wid = threadIdx.x >> 6, lane = threadIdx.x & 63;
  int n = blockIdx.x * 2 + wid;
  int c0 = lane * VPT;
  int hh = c0 / C;
  int rs = row_start[n], re = row_start[n + 1];
  float4 ad4 = *(const float4*)&a_sd[(size_t)n * 8 + 4];
  float bv[VPT];
#pragma unroll
  for (int k = 0; k < VPT; k++) bv[k] = bias[c0 + k];

  __shared__ float s_w[2][64][4];   // per-wave alpha staging (2KB)
  float dp[4] = {0.f, 0.f, 0.f, 0.f};
  float acc[VPT] = {};
  const unsigned short* hbase = (const unsigned short*)hfeat;

  // prologue: chunk 0 csr + a_sd
  int base = rs;
  int cnt = min(64, re - rs);
  int srcv = 0;
  float4 as4 = {0.f, 0.f, 0.f, 0.f};
  if (lane < cnt) {
    srcv = csr_src[rs + lane];
    as4 = *(const float4*)&a_sd[(size_t)srcv * 8];
  }

  while (base < re) {
    float w0 = 0.f, w1 = 0.f, w2 = 0.f, w3 = 0.f;
    if (lane < cnt) {
      w0 = __expf(lrelu(as4.x + ad4.x));
      w1 = __expf(lrelu(as4.y + ad4.y));
      w2 = __expf(lrelu(as4.z + ad4.z));
      w3 = __expf(lrelu(as4.w + ad4.w));
    }
    dp[0] += w0; dp[1] += w1; dp[2] += w2; dp[3] += w3;
    float4 wv = {w0, w1, w2, w3};
    *(float4*)&s_w[wid][lane][0] = wv;
    // within-wave LDS write->read ordering (cross-wave sync illegal here)
    asm volatile("s_waitcnt lgkmcnt(0)" ::: "memory");
    int cur_src = srcv;
    int cur_cnt = cnt;
    // prefetch next chunk's csr_src (independent load, hides under gather)
    int nbase = base + 64;
    bool have_next = nbase < re;
    cnt = min(64, re - nbase);
    srcv = 0;
    if (have_next && lane < cnt) srcv = csr_src[nbase + lane];
    float4 nas4 = {0.f, 0.f, 0.f, 0.f};
    bool did_asd = false;

    int j = 0;
    for (; j + BATCH <= cur_cnt; j += BATCH) {
      int srs[BATCH];
#pragma unroll
      for (int k = 0; k < BATCH; k++) srs[k] = __builtin_amdgcn_readlane(cur_src, j + k);
      if constexpr (VPT == 8) {
        u16x8 v[BATCH];
#pragma unroll
        for (int k = 0; k < BATCH; k++)
          v[k] = *(const u16x8*)&hbase[(size_t)srs[k] * HC + c0];
        if (j == BATCH && have_next) {   // csr prefetch has landed; issue a_sd
          if (lane < cnt) nas4 = *(const float4*)&a_sd[(size_t)srcv * 8];
          did_asd = true;
        }
#pragma unroll
        for (int k = 0; k < BATCH; k++) {
          float av = s_w[wid][j + k][hh];
#pragma unroll
          for (int q = 0; q < 8; q++) acc[q] = fmaf(av, b2f(v[k][q]), acc[q]);
        }
      } else {
        ushort4 v[BATCH];
#pragma unroll
        for (int k = 0; k < BATCH; k++)
          v[k] = *(const ushort4*)&hbase[(size_t)srs[k] * HC + c0];
        if (j == BATCH && have_next) {
          if (lane < cnt) nas4 = *(const float4*)&a_sd[(size_t)srcv * 8];
          did_asd = true;
        }
#pragma unroll
        for (int k = 0; k < BATCH; k++) {
          float av = s_w[wid][j + k][hh];
          acc[0] = fmaf(av, b2f(v[k].x), acc[0]);
          acc[1] = fmaf(av, b2f(v[k].y), acc[1]);
          acc[2] = fmaf(av, b2f(v[k].z), acc[2]);
          acc[3] = fmaf(av, b2f(v[k].w), acc[3]);
        }
      }
    }
    if (have_next && !did_asd && lane < cnt)
      nas4 = *(const float4*)&a_sd[(size_t)srcv * 8];
    for (; j < cur_cnt; j++) {
      int sr = __builtin_amdgcn_readlane(cur_src, j);
      float av = s_w[wid][j][hh];
      const unsigned short* hp = &hbase[(size_t)sr * HC + c0];
      if constexpr (VPT == 8) {
        u16x8 v = *(const u16x8*)hp;
#pragma unroll
        for (int q = 0; q < 8; q++) acc[q] = fmaf(av, b2f(v[q]), acc[q]);
      } else {
        ushort4 v = *(const ushort4*)hp;
        acc[0] = fmaf(av, b2f(v.x), acc[0]);
        acc[1] = fmaf(av, b2f(v.y), acc[1]);
        acc[2] = fmaf(av, b2f(v.z), acc[2]);
        acc[3] = fmaf(av, b2f(v.w), acc[3]);
      }
    }
    as4 = nas4;
    base = nbase;
  }

  // ---- denominator: butterfly-sum the 4 heads, select own head ----
#pragma unroll
  for (int off = 32; off > 0; off >>= 1) {
#pragma unroll
    for (int h = 0; h < 4; h++) dp[h] += __shfl_xor(dp[h], off);
  }
  float dsel = hh == 0 ? dp[0] : hh == 1 ? dp[1] : hh == 2 ? dp[2] : dp[3];
  float inv = 1.f / (dsel + 1e-16f);

  // ---- epilogue ----
#pragma unroll
  for (int k = 0; k < VPT; k++)
    acc[k] = fmaxf(fmaf(acc[k], inv, bv[k]), 0.f);
  if constexpr (OUTBF16) {
    if constexpr (VPT == 8) {
      u16x8 ov;
#pragma unroll
      for (int k = 0; k < 8; k++) ov[k] = f2b(acc[k]);
      *(u16x8*)((unsigned short*)out + (size_t)n * HC + c0) = ov;
    } else {
      ushort4 ov = {f2b(acc[0]), f2b(acc[1]), f2b(acc[2]), f2b(acc[3])};
      *(ushort4*)((unsigned short*)out + (size_t)n * HC + c0) = ov;
    }
  } else {
#pragma unroll
    for (int k = 0; k < VPT; k++) ((float*)out)[(size_t)n * HC + c0 + k] = acc[k];
  }

  // ---- fused a_sd2 = relu_out1[n] @ wa2 (layer-1 instance only) ----
  if constexpr (ASD2) {
    float p[8] = {};
#pragma unroll
    for (int q = 0; q < VPT; q++) {
      const float* wr = &wa2[(size_t)(c0 + q) * 8];
#pragma unroll
      for (int o = 0; o < 8; o++) p[o] = fmaf(acc[q], wr[o], p[o]);
    }
#pragma unroll
    for (int off = 32; off > 0; off >>= 1) {
#pragma unroll
      for (int o = 0; o < 8; o++) p[o] += __shfl_xor(p[o], off);
    }
    if (lane == 0) {
      float4 p0 = {p[0], p[1], p[2], p[3]};
      float4 p1 = {p[4], p[5], p[6], p[7]};
      *(float4*)&a_sd2[(size_t)n * 8 + 0] = p0;
      *(float4*)&a_sd2[(size_t)n * 8 + 4] = p1;
    }
  }
}

// ================= pooled column sum (bf16 in, f32 atomic out) =================
__global__ __launch_bounds__(512) void col_sum_bf16(const __hip_bfloat16* __restrict__ x,
                                                    float* __restrict__ pooled) {
  int t = threadIdx.x;
  float acc = 0.f;
  for (int r = blockIdx.x; r < L; r += 64)
    acc += b2f(*(const unsigned short*)&x[(size_t)r * 512 + t]);
  atomicAdd(&pooled[t], acc);
}

// ================= FC head (pre-transposed f32 weights) =================
__global__ __launch_bounds__(256) void fc1(const float* __restrict__ pooled,
                                           const float* __restrict__ Wt,
                                           const float* __restrict__ b,
                                           float* __restrict__ out) {
  __shared__ float pv[512];
  __shared__ float red[256];
  int t = threadIdx.x;
  pv[t] = pooled[t]; pv[t + 256] = pooled[t + 256];
  __syncthreads();
  int ol = t >> 4;
  int o = blockIdx.x * 16 + ol;
  int ks = (t & 15) * 32;
  float p = 0.f;
  const float* wr = &Wt[(size_t)o * 512 + ks];
#pragma unroll
  for (int kk = 0; kk < 32; kk++) p = fmaf(pv[ks + kk], wr[kk], p);
  red[t] = p;
  __syncthreads();
  if ((t & 15) == 0) {
    float s2 = 0.f;
#pragma unroll
    for (int i = 0; i < 16; i++) s2 += red[ol * 16 + i];
    out[o] = fmaxf(s2 + b[o], 0.f);
  }
}

__global__ __launch_bounds__(256) void fc2(const float* __restrict__ h,
                                           const float* __restrict__ Wt,
                                           const float* __restrict__ outb,
                                           float* __restrict__ out) {
  __shared__ float pv[512];
  __shared__ float red[256];
  int t = threadIdx.x;
  pv[t] = h[t]; pv[t + 256] = h[t + 256];
  __syncthreads();
  int ol = t >> 4;
  int o = blockIdx.x * 16 + ol;
  int ks = (t & 15) * 32;
  float p = 0.f;
  const float* wr = &Wt[(size_t)o * 512 + ks];
#pragma unroll
  for (int kk = 0; kk < 32; kk++) p = fmaf(pv[ks + kk], wr[kk], p);
  red[t] = p;
  __syncthreads();
  if ((t & 15) == 0 && o < 489) {
    float s2 = 0.f;
#pragma unroll
    for (int i = 0; i < 16; i++) s2 += red[ol * 16 + i];
    out[o] = s2 + outb[o];
  }
}

extern "C" void kernel_launch(void* const* d_in, const int* in_sizes, int n_in,
                              void* d_out, int out_size, void* d_ws, size_t ws_size,
                              hipStream_t stream) {
  const float* seq   = (const float*)d_in[0];
  const int*   ei    = (const int*)d_in[1];
  const float* W1    = (const float*)d_in[2];
  const float* W2    = (const float*)d_in[3];
  const float* Wg1   = (const float*)d_in[4];
  const float* asrc1 = (const float*)d_in[5];
  const float* adst1 = (const float*)d_in[6];
  const float* b1    = (const float*)d_in[7];
  const float* Wg2   = (const float*)d_in[8];
  const float* asrc2 = (const float*)d_in[9];
  const float* adst2 = (const float*)d_in[10];
  const float* b2    = (const float*)d_in[11];
  const float* fcW   = (const float*)d_in[12];
  const float* fcb   = (const float*)d_in[13];
  const float* outW  = (const float*)d_in[14];
  const float* outb  = (const float*)d_in[15];
  float* outp = (float*)d_out;

  const int E = in_sizes[1] / 2;      // 524288
  const int Etot = E + L;             // + self loops

  // ---- workspace layout ----
  char* ws = (char*)d_ws;
  __hip_bfloat16* mlp1 = (__hip_bfloat16*)(ws + 0);           // [L,1024] 16MB
  __hip_bfloat16* out2 = (__hip_bfloat16*)(ws + 0);           // [L,512] 8MB (mlp1 dead)
  __hip_bfloat16* h2   = (__hip_bfloat16*)(ws + (16u << 20)); // [L,512] 8MB
  __hip_bfloat16* x0   = (__hip_bfloat16*)(ws + (24u << 20)); // [L,256] 4MB
  __hip_bfloat16* h1   = (__hip_bfloat16*)(ws + (28u << 20)); // [L,256] 4MB
  __hip_bfloat16* out1 = (__hip_bfloat16*)(ws + (32u << 20)); // [L,256] 4MB
  size_t off = (36u << 20);
  __hip_bfloat16* xb   = (__hip_bfloat16*)(ws + off); off += (size_t)L * 32 * 2;
  __hip_bfloat16* W1t  = (__hip_bfloat16*)(ws + off); off += (size_t)1024 * 32 * 2;
  __hip_bfloat16* W2t  = (__hip_bfloat16*)(ws + off); off += (size_t)256 * 1024 * 2;
  __hip_bfloat16* Wg1t = (__hip_bfloat16*)(ws + off); off += (size_t)256 * 256 * 2;
  __hip_bfloat16* Wg2t = (__hip_bfloat16*)(ws + off); off += (size_t)512 * 256 * 2;
  float* fcWt  = (float*)(ws + off); off += (size_t)512 * 512 * 4;
  float* outWt = (float*)(ws + off); off += (size_t)512 * 512 * 4;
  int* csr_src = (int*)(ws + off); off += (size_t)Etot * 4;
  int* rank    = (int*)(ws + off); off += (size_t)Etot * 4;
  off = (off + 255) & ~(size_t)255;
  int* row_start = (int*)(ws + off); off += (size_t)(L + 1) * 4;
  off = (off + 255) & ~(size_t)255;
  int* deg    = (int*)(ws + off); off += (size_t)L * 4;
  float* a_sd1 = (float*)(ws + off); off += (size_t)L * 8 * 4;
  float* a_sd2 = (float*)(ws + off); off += (size_t)L * 8 * 4;
  float* wa1 = (float*)(ws + off); off += 2048 * 4;
  float* wa2 = (float*)(ws + off); off += 2048 * 4;
  float* pooled = (float*)(ws + off); off += 512 * 4;
  float* hbuf   = (float*)(ws + off); off += 512 * 4;

  // ---- zero deg ----
  hipMemsetAsync(deg, 0, (size_t)L * 4, stream);

  // ---- merged transposes + conversions + wa + degree/rank ----
  int convN = 262144 + 4096 + Etot;
  int convB = (convN + 255) / 256;
  conv_combo<<<992 + convB, 256, 0, stream>>>(
      seq, W1, W2, Wg1, Wg2, fcW, outW, ei, asrc1, adst1, asrc2, adst2, E, Etot,
      xb, W1t, W2t, Wg1t, Wg2t, fcWt, outWt, wa1, wa2, deg, rank);

  // ---- CSR ----
  scan_deg<<<1, 1024, 0, stream>>>(deg, row_start, pooled);
  scatter_edges<<<(Etot + 255) / 256, 256, 0, stream>>>(ei, E, Etot, row_start, rank, csr_src);

  // ---- input MLP ----
  gemm_mfma<32, true, true><<<dim3(16, 128), 256, 0, stream>>>(xb, W1t, mlp1, L, 1024, 32);
  gemm_mfma<64, false, true><<<dim3(4, 128), 256, 0, stream>>>(mlp1, W2t, x0, L, 256, 1024);

  // ---- GAT layer 1 (C=64); epilogue also emits a_sd2 ----
  calc_asd<<<128, 256, 0, stream>>>(x0, wa1, a_sd1);
  gemm_mfma<64, false, true><<<dim3(4, 128), 256, 0, stream>>>(x0, Wg1t, h1, L, 256, 256);
  gat_fused<64, true, true><<<4096, 128, 0, stream>>>(h1, a_sd1, row_start, csr_src, b1, out1, wa2, a_sd2);

  // ---- GAT layer 2 (C=128) ----
  gemm_mfma<64, false, true><<<dim3(8, 128), 256, 0, stream>>>(out1, Wg2t, h2, L, 512, 256);
  gat_fused<128, false, true><<<4096, 128, 0, stream>>>(h2, a_sd2, row_start, csr_src, b2, out2, nullptr, nullptr);

  // ---- pool + FC head ----
  col_sum_bf16<<<64, 512, 0, stream>>>(out2, pooled);
  fc1<<<32, 256, 0, stream>>>(pooled, fcWt, fcb, hbuf);
  fc2<<<31, 256, 0, stream>>>(hbuf, outWt, outb, outp);
}

// Round 7
// 221.660 us; speedup vs baseline: 3.6289x; 1.0762x over previous
//
#include <hip/hip_runtime.h>
#include <hip/hip_bf16.h>

constexpr int L = 8192;          // nodes
constexpr int H = 4;             // heads (both layers)

typedef __attribute__((ext_vector_type(8))) short bf16x8;
typedef __attribute__((ext_vector_type(8))) unsigned short u16x8;
typedef __attribute__((ext_vector_type(4))) float f32x4;

static __device__ __forceinline__ float lrelu(float e) {
  return e > 0.f ? e : 0.2f * e;
}
static __device__ __forceinline__ float b2f(unsigned short s) {
  return __uint_as_float(((unsigned)s) << 16);
}
static __device__ __forceinline__ unsigned short f2b(float f) {
  __hip_bfloat16 h = __float2bfloat16(f);
  return *reinterpret_cast<unsigned short*>(&h);
}

// ========== merged: LDS-tiled transposes (blocks 0..991) + elementwise tail ====
// transpose segments (32x32 tiles): W2(256) Wg1(64) Wg2(128) fcW(256) outW(256) W1(32)
// tail: xb 262144, wa1->Wg1t rows 256..263 (2048), wa2 f32 (2048),
//       Wg1t zero rows 264..319 (14336), deg/rank Etot
__global__ __launch_bounds__(256) void conv_combo(
    const float* __restrict__ seq, const float* __restrict__ W1,
    const float* __restrict__ W2, const float* __restrict__ Wg1,
    const float* __restrict__ Wg2, const float* __restrict__ fcW,
    const float* __restrict__ outW, const int* __restrict__ ei,
    const float* __restrict__ as1, const float* __restrict__ ad1,
    const float* __restrict__ as2, const float* __restrict__ ad2,
    int E, int Etot,
    __hip_bfloat16* __restrict__ xb, __hip_bfloat16* __restrict__ W1t,
    __hip_bfloat16* __restrict__ W2t, __hip_bfloat16* __restrict__ Wg1t,
    __hip_bfloat16* __restrict__ Wg2t, float* __restrict__ fcWt,
    float* __restrict__ outWt, float* __restrict__ wa2,
    int* __restrict__ deg, int* __restrict__ rank) {
  __shared__ float tile[32][33];
  if (blockIdx.x < 992) {
    int b = blockIdx.x;
    const float* src; void* dst; bool obf16; int K, N, Kout, kt, nt;
    if (b < 256)               { src = W2;  dst = W2t;  obf16 = true;  K = 1024; N = 256; Kout = 1024; nt = b & 7;  kt = b >> 3; }
    else if ((b -= 256) < 64)  { src = Wg1; dst = Wg1t; obf16 = true;  K = 256;  N = 256; Kout = 256;  nt = b & 7;  kt = b >> 3; }
    else if ((b -= 64) < 128)  { src = Wg2; dst = Wg2t; obf16 = true;  K = 256;  N = 512; Kout = 256;  nt = b & 15; kt = b >> 4; }
    else if ((b -= 128) < 256) { src = fcW; dst = fcWt; obf16 = false; K = 512;  N = 512; Kout = 512;  nt = b & 15; kt = b >> 4; }
    else if ((b -= 256) < 256) { src = outW;dst = outWt;obf16 = false; K = 512;  N = 489; Kout = 512;  nt = b & 15; kt = b >> 4; }
    else { b -= 256;             src = W1;  dst = W1t;  obf16 = true;  K = 26;   N = 1024;Kout = 32;   nt = b;      kt = 0; }
    int t = threadIdx.x;
    int lr = t >> 3, lc4 = (t & 7) * 4;
    int gk = kt * 32 + lr, gn = nt * 32 + lc4;
    float4 v = {0.f, 0.f, 0.f, 0.f};
    if (gk < K) {
      const float* p = &src[(size_t)gk * N + gn];
      v.x = (gn + 0 < N) ? p[0] : 0.f;
      v.y = (gn + 1 < N) ? p[1] : 0.f;
      v.z = (gn + 2 < N) ? p[2] : 0.f;
      v.w = (gn + 3 < N) ? p[3] : 0.f;
    }
    tile[lr][lc4 + 0] = v.x; tile[lr][lc4 + 1] = v.y;
    tile[lr][lc4 + 2] = v.z; tile[lr][lc4 + 3] = v.w;
    __syncthreads();
    int on = nt * 32 + lr, ok = kt * 32 + lc4;
    if (on >= N || ok >= Kout) return;
    float o0 = tile[lc4 + 0][lr], o1 = tile[lc4 + 1][lr];
    float o2 = tile[lc4 + 2][lr], o3 = tile[lc4 + 3][lr];
    if (obf16) {
      ushort4 u = {f2b(o0), f2b(o1), f2b(o2), f2b(o3)};
      *(ushort4*)&((__hip_bfloat16*)dst)[(size_t)on * Kout + ok] = u;
    } else {
      float4 u = {o0, o1, o2, o3};
      *(float4*)&((float*)dst)[(size_t)on * Kout + ok] = u;
    }
    return;
  }
  int i = (blockIdx.x - 992) * 256 + threadIdx.x;
  if (i < 262144) { int r = i >> 5, k = i & 31;
    xb[i] = __float2bfloat16(k < 26 ? seq[r * 26 + k] : 0.f); return; }
  i -= 262144;
  if (i < 2048) {  // Wg1t extension rows 256..263: wa1[k][o] in bf16
    int k = i >> 3, o = i & 7, h = o & 3;
    const float* av = (o < 4) ? as1 : ad1;
    float s = 0.f;
    for (int c = 0; c < 64; c++) s += Wg1[k * 256 + h * 64 + c] * av[h * 64 + c];
    Wg1t[(size_t)(256 + o) * 256 + k] = __float2bfloat16(s); return; }
  i -= 2048;
  if (i < 2048) {  // wa2 f32 (for gat1's fused a_sd2 epilogue)
    int k = i >> 3, o = i & 7, h = o & 3;
    const float* av = (o < 4) ? as2 : ad2;
    float s = 0.f;
    for (int c = 0; c < 128; c++) s += Wg2[k * 512 + h * 128 + c] * av[h * 128 + c];
    wa2[i] = s; return; }
  i -= 2048;
  if (i < 14336) {  // Wg1t zero rows 264..319
    ((__hip_bfloat16*)Wg1t)[(size_t)264 * 256 + i] = __float2bfloat16(0.f); return; }
  i -= 14336;
  if (i < Etot) {
    int dst = (i < E) ? ei[E + i] : (i - E);
    rank[i] = atomicAdd(&deg[dst], 1);
  }
}

// ============ bf16 MFMA GEMM: C = op(A[M,K] @ Bt[*,K]^T), 128x64 tile =========
// 256 threads = 4 waves in 2(M)x2(N); wave patch 64x32 (4x2 16x16 frags).
// ASD: cols >= N route to asd[row*8 + col-N] as f32 (cols N+8.. dropped).
template<int BK, bool RELU, bool ASD>
__global__ __launch_bounds__(256) void gemm_big(
    const __hip_bfloat16* __restrict__ A, const __hip_bfloat16* __restrict__ Bt,
    __hip_bfloat16* __restrict__ C, float* __restrict__ asd,
    int M, int N, int K) {
  __shared__ __align__(16) short As[128][BK + 8];
  __shared__ __align__(16) short Bs[64][BK + 8];
  int tid = threadIdx.x;
  int m0 = blockIdx.y * 128, n0 = blockIdx.x * 64;
  int w = tid >> 6, lane = tid & 63;
  int wm = (w >> 1) * 64, wn = (w & 1) * 32;
  f32x4 acc[4][2] = {};
  for (int k0 = 0; k0 < K; k0 += BK) {
    if constexpr (BK == 64) {
#pragma unroll
      for (int i = 0; i < 4; i++) {
        int ch = i * 256 + tid; int r = ch >> 3, kg = ch & 7;
        *(bf16x8*)&As[r][kg * 8] = *(const bf16x8*)&A[(size_t)(m0 + r) * K + k0 + kg * 8];
      }
#pragma unroll
      for (int i = 0; i < 2; i++) {
        int ch = i * 256 + tid; int r = ch >> 3, kg = ch & 7;
        *(bf16x8*)&Bs[r][kg * 8] = *(const bf16x8*)&Bt[(size_t)(n0 + r) * K + k0 + kg * 8];
      }
    } else {  // BK == 32
#pragma unroll
      for (int i = 0; i < 2; i++) {
        int ch = i * 256 + tid; int r = ch >> 2, kg = ch & 3;
        *(bf16x8*)&As[r][kg * 8] = *(const bf16x8*)&A[(size_t)(m0 + r) * K + k0 + kg * 8];
      }
      { int r = tid >> 2, kg = tid & 3;
        *(bf16x8*)&Bs[r][kg * 8] = *(const bf16x8*)&Bt[(size_t)(n0 + r) * K + k0 + kg * 8]; }
    }
    __syncthreads();
    int kk = (lane >> 4) * 8;
#pragma unroll
    for (int ks = 0; ks < BK / 32; ks++) {
      bf16x8 af[4], bfr[2];
#pragma unroll
      for (int m = 0; m < 4; m++)
        af[m] = *(const bf16x8*)&As[wm + m * 16 + (lane & 15)][ks * 32 + kk];
#pragma unroll
      for (int n = 0; n < 2; n++)
        bfr[n] = *(const bf16x8*)&Bs[wn + n * 16 + (lane & 15)][ks * 32 + kk];
#pragma unroll
      for (int m = 0; m < 4; m++)
#pragma unroll
        for (int n = 0; n < 2; n++)
          acc[m][n] = __builtin_amdgcn_mfma_f32_16x16x32_bf16(af[m], bfr[n], acc[m][n], 0, 0, 0);
    }
    __syncthreads();
  }
#pragma unroll
  for (int m = 0; m < 4; m++) {
#pragma unroll
    for (int n = 0; n < 2; n++) {
      int col = n0 + wn + n * 16 + (lane & 15);
#pragma unroll
      for (int j = 0; j < 4; j++) {
        int row = m0 + wm + m * 16 + (lane >> 4) * 4 + j;
        float v = acc[m][n][j];
        if (RELU) v = fmaxf(v, 0.f);
        if (!ASD) {
          C[(size_t)row * N + col] = __float2bfloat16(v);
        } else {
          if (col < N) C[(size_t)row * N + col] = __float2bfloat16(v);
          else if (col < N + 8) asd[(size_t)row * 8 + (col - N)] = v;
        }
      }
    }
  }
}

// ================= CSR build: shuffle-based scan (1 barrier) =================
__global__ __launch_bounds__(1024) void scan_deg(const int* __restrict__ deg,
                                                 int* __restrict__ row_start,
                                                 float* __restrict__ pooled) {
  __shared__ int wsum[16];
  int t = threadIdx.x;
  if (t < 512) pooled[t] = 0.f;
  int lane = t & 63, w = t >> 6;
  int local[8];
  int sum = 0;
#pragma unroll
  for (int j = 0; j < 8; j++) { local[j] = deg[t * 8 + j]; sum += local[j]; }
  int v = sum;
#pragma unroll
  for (int off = 1; off < 64; off <<= 1) {
    int u = __shfl_up(v, off);
    if (lane >= off) v += u;
  }
  if (lane == 63) wsum[w] = v;
  __syncthreads();
  int woff = 0;
  for (int i = 0; i < w; i++) woff += wsum[i];
  int base = woff + v - sum;   // exclusive prefix
#pragma unroll
  for (int j = 0; j < 8; j++) { row_start[t * 8 + j] = base; base += local[j]; }
  if (t == 1023) row_start[L] = base;
}

// atomic-free scatter using precomputed ranks
__global__ void scatter_edges(const int* __restrict__ ei, int E, int Etot,
                              const int* __restrict__ row_start,
                              const int* __restrict__ rank, int* __restrict__ csr_src) {
  int e = blockIdx.x * blockDim.x + threadIdx.x;
  if (e >= Etot) return;
  int srcv, dstv;
  if (e < E) { srcv = ei[e]; dstv = ei[E + e]; } else { srcv = dstv = e - E; }
  csr_src[row_start[dstv] + rank[e]] = srcv;
}

// ====== fused single-sweep softmax+aggregate, chunk-pipelined; 1 wave/node =====
// acc = sum_j exp(e_j)*h[src_j] (unnormalized) + denom; divide at end.
// PHASES: channel-phase split (blockIdx.y) so the per-phase gathered table
// footprint fits a 4MB per-XCD L2 (layer 2: 8MB table -> 2 x 4MB phases).
// ASD2: layer-1 instance also emits a_sd2[n][8] = relu_out1[n] @ wa2.
template<int C, int PHASES, bool ASD2>
__global__ __launch_bounds__(128) void gat_fused(
    const __hip_bfloat16* __restrict__ hfeat, const float* __restrict__ a_sd,
    const int* __restrict__ row_start, const int* __restrict__ csr_src,
    const float* __restrict__ bias, __hip_bfloat16* __restrict__ out,
    const float* __restrict__ wa2, float* __restrict__ a_sd2) {
  constexpr int HC = 4 * C;
  constexpr int CP = HC / PHASES;       // channels this phase (always 256)
  constexpr int BATCH = 16;             // in-flight row gathers
  static_assert(CP == 256, "phase width must be 256");
  int wid = threadIdx.x >> 6, lane = threadIdx.x & 63;
  int n = blockIdx.x * 2 + wid;
  int c0 = blockIdx.y * CP + lane * 4;
  int hh = c0 / C;
  int rs = row_start[n], re = row_start[n + 1];
  float4 ad4 = *(const float4*)&a_sd[(size_t)n * 8 + 4];
  float bv[4];
#pragma unroll
  for (int k = 0; k < 4; k++) bv[k] = bias[c0 + k];

  __shared__ float s_w[2][64][4];   // per-wave alpha staging (2KB)
  float dp[4] = {0.f, 0.f, 0.f, 0.f};
  float acc[4] = {0.f, 0.f, 0.f, 0.f};
  const unsigned short* hbase = (const unsigned short*)hfeat;

  // prologue: chunk 0 csr + a_sd
  int base = rs;
  int cnt = min(64, re - rs);
  int srcv = 0;
  float4 as4 = {0.f, 0.f, 0.f, 0.f};
  if (lane < cnt) {
    srcv = csr_src[rs + lane];
    as4 = *(const float4*)&a_sd[(size_t)srcv * 8];
  }

  while (base < re) {
    float w0 = 0.f, w1 = 0.f, w2 = 0.f, w3 = 0.f;
    if (lane < cnt) {
      w0 = __expf(lrelu(as4.x + ad4.x));
      w1 = __expf(lrelu(as4.y + ad4.y));
      w2 = __expf(lrelu(as4.z + ad4.z));
      w3 = __expf(lrelu(as4.w + ad4.w));
    }
    dp[0] += w0; dp[1] += w1; dp[2] += w2; dp[3] += w3;
    float4 wv = {w0, w1, w2, w3};
    *(float4*)&s_w[wid][lane][0] = wv;
    // within-wave LDS write->read ordering (cross-wave sync illegal here)
    asm volatile("s_waitcnt lgkmcnt(0)" ::: "memory");
    int cur_src = srcv;
    int cur_cnt = cnt;
    // prefetch next chunk's csr_src (independent load, hides under gather)
    int nbase = base + 64;
    bool have_next = nbase < re;
    cnt = min(64, re - nbase);
    srcv = 0;
    if (have_next && lane < cnt) srcv = csr_src[nbase + lane];
    float4 nas4 = {0.f, 0.f, 0.f, 0.f};
    bool did_asd = false;

    int j = 0;
    for (; j + BATCH <= cur_cnt; j += BATCH) {
      int srs[BATCH];
#pragma unroll
      for (int k = 0; k < BATCH; k++) srs[k] = __builtin_amdgcn_readlane(cur_src, j + k);
      ushort4 v[BATCH];
#pragma unroll
      for (int k = 0; k < BATCH; k++)
        v[k] = *(const ushort4*)&hbase[(size_t)srs[k] * HC + c0];
      if (j == BATCH && have_next) {   // csr prefetch has landed; issue a_sd
        if (lane < cnt) nas4 = *(const float4*)&a_sd[(size_t)srcv * 8];
        did_asd = true;
      }
#pragma unroll
      for (int k = 0; k < BATCH; k++) {
        float av = s_w[wid][j + k][hh];
        acc[0] = fmaf(av, b2f(v[k].x), acc[0]);
        acc[1] = fmaf(av, b2f(v[k].y), acc[1]);
        acc[2] = fmaf(av, b2f(v[k].z), acc[2]);
        acc[3] = fmaf(av, b2f(v[k].w), acc[3]);
      }
    }
    if (have_next && !did_asd && lane < cnt)
      nas4 = *(const float4*)&a_sd[(size_t)srcv * 8];
    for (; j < cur_cnt; j++) {
      int sr = __builtin_amdgcn_readlane(cur_src, j);
      float av = s_w[wid][j][hh];
      ushort4 v = *(const ushort4*)&hbase[(size_t)sr * HC + c0];
      acc[0] = fmaf(av, b2f(v.x), acc[0]);
      acc[1] = fmaf(av, b2f(v.y), acc[1]);
      acc[2] = fmaf(av, b2f(v.z), acc[2]);
      acc[3] = fmaf(av, b2f(v.w), acc[3]);
    }
    as4 = nas4;
    base = nbase;
  }

  // ---- denominator: butterfly-sum the 4 heads, select own head ----
#pragma unroll
  for (int off = 32; off > 0; off >>= 1) {
#pragma unroll
    for (int h = 0; h < 4; h++) dp[h] += __shfl_xor(dp[h], off);
  }
  float dsel = hh == 0 ? dp[0] : hh == 1 ? dp[1] : hh == 2 ? dp[2] : dp[3];
  float inv = 1.f / (dsel + 1e-16f);

  // ---- epilogue ----
#pragma unroll
  for (int k = 0; k < 4; k++)
    acc[k] = fmaxf(fmaf(acc[k], inv, bv[k]), 0.f);
  ushort4 ov = {f2b(acc[0]), f2b(acc[1]), f2b(acc[2]), f2b(acc[3])};
  *(ushort4*)((unsigned short*)out + (size_t)n * HC + c0) = ov;

  // ---- fused a_sd2 = relu_out1[n] @ wa2 (layer-1 instance only) ----
  if constexpr (ASD2) {
    float p[8] = {};
#pragma unroll
    for (int q = 0; q < 4; q++) {
      const float* wr = &wa2[(size_t)(c0 + q) * 8];
#pragma unroll
      for (int o = 0; o < 8; o++) p[o] = fmaf(acc[q], wr[o], p[o]);
    }
#pragma unroll
    for (int off = 32; off > 0; off >>= 1) {
#pragma unroll
      for (int o = 0; o < 8; o++) p[o] += __shfl_xor(p[o], off);
    }
    if (lane == 0) {
      float4 p0 = {p[0], p[1], p[2], p[3]};
      float4 p1 = {p[4], p[5], p[6], p[7]};
      *(float4*)&a_sd2[(size_t)n * 8 + 0] = p0;
      *(float4*)&a_sd2[(size_t)n * 8 + 4] = p1;
    }
  }
}

// ================= pooled column sum (bf16 in, f32 atomic out) =================
__global__ __launch_bounds__(512) void col_sum_bf16(const __hip_bfloat16* __restrict__ x,
                                                    float* __restrict__ pooled) {
  int t = threadIdx.x;
  float acc = 0.f;
  for (int r = blockIdx.x; r < L; r += 64)
    acc += b2f(*(const unsigned short*)&x[(size_t)r * 512 + t]);
  atomicAdd(&pooled[t], acc);
}

// ================= FC head (pre-transposed f32 weights) =================
__global__ __launch_bounds__(256) void fc1(const float* __restrict__ pooled,
                                           const float* __restrict__ Wt,
                                           const float* __restrict__ b,
                                           float* __restrict__ out) {
  __shared__ float pv[512];
  __shared__ float red[256];
  int t = threadIdx.x;
  pv[t] = pooled[t]; pv[t + 256] = pooled[t + 256];
  __syncthreads();
  int ol = t >> 4;
  int o = blockIdx.x * 16 + ol;
  int ks = (t & 15) * 32;
  float p = 0.f;
  const float* wr = &Wt[(size_t)o * 512 + ks];
#pragma unroll
  for (int kk = 0; kk < 32; kk++) p = fmaf(pv[ks + kk], wr[kk], p);
  red[t] = p;
  __syncthreads();
  if ((t & 15) == 0) {
    float s2 = 0.f;
#pragma unroll
    for (int i = 0; i < 16; i++) s2 += red[ol * 16 + i];
    out[o] = fmaxf(s2 + b[o], 0.f);
  }
}

__global__ __launch_bounds__(256) void fc2(const float* __restrict__ h,
                                           const float* __restrict__ Wt,
                                           const float* __restrict__ outb,
                                           float* __restrict__ out) {
  __shared__ float pv[512];
  __shared__ float red[256];
  int t = threadIdx.x;
  pv[t] = h[t]; pv[t + 256] = h[t + 256];
  __syncthreads();
  int ol = t >> 4;
  int o = blockIdx.x * 16 + ol;
  int ks = (t & 15) * 32;
  float p = 0.f;
  const float* wr = &Wt[(size_t)o * 512 + ks];
#pragma unroll
  for (int kk = 0; kk < 32; kk++) p = fmaf(pv[ks + kk], wr[kk], p);
  red[t] = p;
  __syncthreads();
  if ((t & 15) == 0 && o < 489) {
    float s2 = 0.f;
#pragma unroll
    for (int i = 0; i < 16; i++) s2 += red[ol * 16 + i];
    out[o] = s2 + outb[o];
  }
}

extern "C" void kernel_launch(void* const* d_in, const int* in_sizes, int n_in,
                              void* d_out, int out_size, void* d_ws, size_t ws_size,
                              hipStream_t stream) {
  const float* seq   = (const float*)d_in[0];
  const int*   ei    = (const int*)d_in[1];
  const float* W1    = (const float*)d_in[2];
  const float* W2    = (const float*)d_in[3];
  const float* Wg1   = (const float*)d_in[4];
  const float* asrc1 = (const float*)d_in[5];
  const float* adst1 = (const float*)d_in[6];
  const float* b1    = (const float*)d_in[7];
  const float* Wg2   = (const float*)d_in[8];
  const float* asrc2 = (const float*)d_in[9];
  const float* adst2 = (const float*)d_in[10];
  const float* b2    = (const float*)d_in[11];
  const float* fcW   = (const float*)d_in[12];
  const float* fcb   = (const float*)d_in[13];
  const float* outW  = (const float*)d_in[14];
  const float* outb  = (const float*)d_in[15];
  float* outp = (float*)d_out;

  const int E = in_sizes[1] / 2;      // 524288
  const int Etot = E + L;             // + self loops

  // ---- workspace layout ----
  char* ws = (char*)d_ws;
  __hip_bfloat16* mlp1 = (__hip_bfloat16*)(ws + 0);           // [L,1024] 16MB
  __hip_bfloat16* out2 = (__hip_bfloat16*)(ws + 0);           // [L,512] 8MB (mlp1 dead)
  __hip_bfloat16* h2   = (__hip_bfloat16*)(ws + (16u << 20)); // [L,512] 8MB
  __hip_bfloat16* x0   = (__hip_bfloat16*)(ws + (24u << 20)); // [L,256] 4MB
  __hip_bfloat16* h1   = (__hip_bfloat16*)(ws + (28u << 20)); // [L,256] 4MB
  __hip_bfloat16* out1 = (__hip_bfloat16*)(ws + (32u << 20)); // [L,256] 4MB
  size_t off = (36u << 20);
  __hip_bfloat16* xb   = (__hip_bfloat16*)(ws + off); off += (size_t)L * 32 * 2;
  __hip_bfloat16* W1t  = (__hip_bfloat16*)(ws + off); off += (size_t)1024 * 32 * 2;
  __hip_bfloat16* W2t  = (__hip_bfloat16*)(ws + off); off += (size_t)256 * 1024 * 2;
  __hip_bfloat16* Wg1t = (__hip_bfloat16*)(ws + off); off += (size_t)320 * 256 * 2;  // extended
  __hip_bfloat16* Wg2t = (__hip_bfloat16*)(ws + off); off += (size_t)512 * 256 * 2;
  float* fcWt  = (float*)(ws + off); off += (size_t)512 * 512 * 4;
  float* outWt = (float*)(ws + off); off += (size_t)512 * 512 * 4;
  int* csr_src = (int*)(ws + off); off += (size_t)Etot * 4;
  int* rank    = (int*)(ws + off); off += (size_t)Etot * 4;
  off = (off + 255) & ~(size_t)255;
  int* row_start = (int*)(ws + off); off += (size_t)(L + 1) * 4;
  off = (off + 255) & ~(size_t)255;
  int* deg    = (int*)(ws + off); off += (size_t)L * 4;
  float* a_sd1 = (float*)(ws + off); off += (size_t)L * 8 * 4;
  float* a_sd2 = (float*)(ws + off); off += (size_t)L * 8 * 4;
  float* wa2 = (float*)(ws + off); off += 2048 * 4;
  float* pooled = (float*)(ws + off); off += 512 * 4;
  float* hbuf   = (float*)(ws + off); off += 512 * 4;

  // ---- zero deg ----
  hipMemsetAsync(deg, 0, (size_t)L * 4, stream);

  // ---- merged transposes + conversions + wa + degree/rank ----
  int convN = 262144 + 2048 + 2048 + 14336 + Etot;
  int convB = (convN + 255) / 256;
  conv_combo<<<992 + convB, 256, 0, stream>>>(
      seq, W1, W2, Wg1, Wg2, fcW, outW, ei, asrc1, adst1, asrc2, adst2, E, Etot,
      xb, W1t, W2t, Wg1t, Wg2t, fcWt, outWt, wa2, deg, rank);

  // ---- CSR ----
  scan_deg<<<1, 1024, 0, stream>>>(deg, row_start, pooled);
  scatter_edges<<<(Etot + 255) / 256, 256, 0, stream>>>(ei, E, Etot, row_start, rank, csr_src);

  // ---- input MLP ----
  gemm_big<32, true, false><<<dim3(16, 64), 256, 0, stream>>>(xb, W1t, mlp1, nullptr, L, 1024, 32);
  gemm_big<64, false, false><<<dim3(4, 64), 256, 0, stream>>>(mlp1, W2t, x0, nullptr, L, 256, 1024);

  // ---- GAT layer 1 (C=64): h1 GEMM also emits a_sd1 via extended Wg1t ----
  gemm_big<64, false, true><<<dim3(5, 64), 256, 0, stream>>>(x0, Wg1t, h1, a_sd1, L, 256, 256);
  gat_fused<64, 1, true><<<dim3(4096, 1), 128, 0, stream>>>(h1, a_sd1, row_start, csr_src, b1, out1, wa2, a_sd2);

  // ---- GAT layer 2 (C=128), channel-phase-split gather ----
  gemm_big<64, false, false><<<dim3(8, 64), 256, 0, stream>>>(out1, Wg2t, h2, nullptr, L, 512, 256);
  gat_fused<128, 2, false><<<dim3(4096, 2), 128, 0, stream>>>(h2, a_sd2, row_start, csr_src, b2, out2, nullptr, nullptr);

  // ---- pool + FC head ----
  col_sum_bf16<<<64, 512, 0, stream>>>(out2, pooled);
  fc1<<<32, 256, 0, stream>>>(pooled, fcWt, fcb, hbuf);
  fc2<<<31, 256, 0, stream>>>(hbuf, outWt, outb, outp);
}